// Round 10
// baseline (1082.958 us; speedup 1.0000x reference)
//
#include <hip/hip_runtime.h>
#include <cstddef>
#include <cstdint>

typedef __attribute__((ext_vector_type(8))) short bf16x8;
typedef __attribute__((ext_vector_type(16))) float f32x16;
typedef __attribute__((ext_vector_type(4))) unsigned short us4;

// ---------------- workspace layout (byte offsets) ----------------
static const size_t B_BIASC = 0;            // 6*160*4 = 3,840
static const size_t B_KTH   = 3840;         // 20*1024*32*2 = 1,310,720
static const size_t B_KTL   = 1314560;      // 1,310,720
static const size_t B_VT    = 2625280;      // 20*128*1024*2 = 5,242,880
static const size_t B_KQH   = 7868160;      // 5*2*1024*32*2 = 655,360
static const size_t B_KQL   = 8523520;      // 655,360
static const size_t B_VQ    = 9178880;      // 5*2*128*1024*2 = 2,621,440
static const size_t B_MEAN  = 11800320;     // 5*512*4 = 10,240
static const size_t B_FSM   = 11810560;     // 5*2*256*1024*2 = 5,242,880 (bf16)
static const size_t B_MU    = 17053440;     // 5*256*4 = 5,120
static const size_t B_VAR   = 17058560;     // 5,120
static const size_t B_WC    = 17063680;     // 5*256*512*2 = 1,310,720
static const size_t B_BIAS2 = 18374400;     // 5,120
static const size_t B_UNION = 18379520;     // 40,304,640 union region
// phase 1: X_all_hi +0 (15,728,640), X_all_lo +15,728,640, wp_hi +31,457,280, wp_lo +35,880,960
// phase 2 (per level): fin_part +0 (20*2*256*1024*2 = 20,971,520) -> reduce20 -> fsm;
//                      then fin_big fp32 +0 (<=33,554,432) overwrites it
static const size_t U_XH    = 0;
static const size_t U_XL    = 15728640;
static const size_t U_WPH   = 31457280;
static const size_t U_WPL   = 35880960;
static const size_t U_FPART = 0;
static const size_t WS_BYTES = 58684160;    // ~58.7 MB

// ---------------- bf16 helpers (RNE) ----------------
__device__ inline unsigned short f2bf(float x) {
    unsigned u = __float_as_uint(x);
    return (unsigned short)((u + 0x7fffu + ((u >> 16) & 1u)) >> 16);
}
__device__ inline float bf2f(unsigned short u) {
    return __uint_as_float(((unsigned)u) << 16);
}
__device__ inline void bf16split(float x, unsigned short& hi, unsigned short& lo) {
    unsigned u = __float_as_uint(x);
    unsigned hb = (u + 0x7fffu + ((u >> 16) & 1u)) >> 16;
    hi = (unsigned short)hb;
    float hf = __uint_as_float(hb << 16);
    float r = x - hf;
    unsigned ur = __float_as_uint(r);
    lo = (unsigned short)((ur + 0x7fffu + ((ur >> 16) & 1u)) >> 16);
}
__device__ inline const float* sel5(const float* a, const float* b, const float* c,
                                    const float* d, const float* e, int i) {
    return i == 0 ? a : i == 1 ? b : i == 2 ? c : i == 3 ? d : e;
}

// ---------------- weight pre-transform ----------------
__global__ __launch_bounds__(256) void prep_weights(
    const float* __restrict__ kt_w, const float* __restrict__ kt_b,
    const float* __restrict__ vt_w, const float* __restrict__ vt_b,
    const float* __restrict__ kq_w, const float* __restrict__ kq_b,
    const float* __restrict__ vq_w, const float* __restrict__ vq_b,
    short* __restrict__ wp_hi, short* __restrict__ wp_lo, float* __restrict__ biasc)
{
    const int oc = blockIdx.x;    // 0..159
    const int s  = blockIdx.y;    // 0..5 (0 = stage A, 1+idx = level)
    const int ic = threadIdx.x;   // 0..255
    const bool iskey = oc < 32;
    const int ocl = iskey ? oc : oc - 32;
    const float scale = (iskey && s > 0) ? 1.4426950408889634f : 1.0f;
    const float* w = iskey
        ? (s == 0 ? kt_w : kq_w + (size_t)(s - 1) * 32 * 256 * 9)
        : (s == 0 ? vt_w : vq_w + (size_t)(s - 1) * 128 * 256 * 9);
    const float* wsrc = w + ((size_t)ocl * 256 + ic) * 9;
#pragma unroll
    for (int t = 0; t < 9; ++t) {
        unsigned short h, l; bf16split(wsrc[t] * scale, h, l);
        size_t d = ((size_t)(s * 9 + t) * 160 + oc) * 256 + ic;
        wp_hi[d] = (short)h; wp_lo[d] = (short)l;
    }
    if (ic == 0) {
        const float* bptr = iskey
            ? (s == 0 ? kt_b : kq_b + (s - 1) * 32)
            : (s == 0 ? vt_b : vq_b + (s - 1) * 128);
        biasc[s * 160 + oc] = bptr[ocl] * scale;
    }
}

// ---------------- fp32 [20][256][1024] -> bf16 hi/lo X_all imgs 0..19 ----------------
__global__ __launch_bounds__(256) void transpose_split(
    const float* __restrict__ in,
    unsigned short* __restrict__ oh, unsigned short* __restrict__ ol)
{
    __shared__ float s[16][260];
    const int n = blockIdx.x, ch = blockIdx.y, p0 = blockIdx.z * 256;
    const int tid = threadIdx.x;
#pragma unroll
    for (int i = 0; i < 16; ++i)
        s[i][tid] = in[((size_t)(n * 256 + ch * 16 + i)) * 1024 + p0 + tid];
    __syncthreads();
    union { unsigned short u[16]; bf16x8 v[2]; } h8, l8;
#pragma unroll
    for (int i = 0; i < 16; ++i) bf16split(s[i][tid], h8.u[i], l8.u[i]);
    size_t base = ((size_t)(n * 16 + ch) * 1024 + p0 + tid) * 16;
    *(bf16x8*)&oh[base] = h8.v[0]; *(bf16x8*)&oh[base + 8] = h8.v[1];
    *(bf16x8*)&ol[base] = l8.v[0]; *(bf16x8*)&ol[base + 8] = l8.v[1];
}

// ---------------- batched per (lvl,b,c) spatial mean ----------------
__global__ __launch_bounds__(256) void mean2d_all(
    const float* f0, const float* f1, const float* f2, const float* f3, const float* f4,
    float* __restrict__ mean)
{
    const int lvl = blockIdx.y;
    const float* f = sel5(f0, f1, f2, f3, f4, lvl);
    const int H = 128 >> lvl, HW = H * H;
    const int bc = blockIdx.x;
    const float* src = f + (size_t)bc * HW;
    float s = 0.f;
    for (int i = threadIdx.x; i < HW; i += 256) s += src[i];
#pragma unroll
    for (int off = 32; off; off >>= 1) s += __shfl_xor(s, off);
    __shared__ float red[4];
    if ((threadIdx.x & 63) == 0) red[threadIdx.x >> 6] = s;
    __syncthreads();
    if (threadIdx.x == 0)
        mean[lvl * 512 + bc] = (red[0] + red[1] + red[2] + red[3]) / (float)HW;
}

// ---------------- batched resize (HxH->32x32) + mean-sub -> X_all imgs 20..29 ----------------
__global__ __launch_bounds__(256) void resizeT_all(
    const float* f0, const float* f1, const float* f2, const float* f3, const float* f4,
    const float* __restrict__ mean,
    unsigned short* __restrict__ oh, unsigned short* __restrict__ ol)
{
    __shared__ float s[16][260];
    const int lvl = blockIdx.z >> 2;
    const int p0 = (blockIdx.z & 3) * 256;
    const int b = blockIdx.x, ch = blockIdx.y;
    const float* f = sel5(f0, f1, f2, f3, f4, lvl);
    const int H = 128 >> lvl;
    const int img = 20 + lvl * 2 + b;
    const int tid = threadIdx.x;
    const int p = p0 + tid, y = p >> 5, x = p & 31;
    float fy = (float)y * (float)(H - 1) / 31.0f;
    float fx = (float)x * (float)(H - 1) / 31.0f;
    int y0 = (int)fy; int y1 = min(y0 + 1, H - 1); float wy = fy - (float)y0;
    int x0 = (int)fx; int x1 = min(x0 + 1, H - 1); float wx = fx - (float)x0;
#pragma unroll
    for (int i = 0; i < 16; ++i) {
        int c = ch * 16 + i;
        const float* pf = f + ((size_t)(b * 256 + c)) * H * H;
        float a = pf[y0 * H + x0], bb = pf[y1 * H + x0];
        float cc = pf[y0 * H + x1], d = pf[y1 * H + x1];
        float c0 = a + (bb - a) * wy;
        float c1 = cc + (d - cc) * wy;
        s[i][tid] = c0 + (c1 - c0) * wx - mean[lvl * 512 + b * 256 + c];
    }
    __syncthreads();
    union { unsigned short u[16]; bf16x8 v[2]; } h8, l8;
#pragma unroll
    for (int i = 0; i < 16; ++i) bf16split(s[i][tid], h8.u[i], l8.u[i]);
    size_t base = ((size_t)(img * 16 + ch) * 1024 + p) * 16;
    *(bf16x8*)&oh[base] = h8.v[0]; *(bf16x8*)&oh[base + 8] = h8.v[1];
    *(bf16x8*)&ol[base] = l8.v[0]; *(bf16x8*)&ol[base + 8] = l8.v[1];
}

// ---------------- merged direct MFMA 3x3 conv: ic split across waves + LDS reduce ----------------
// grid (30 img, 16 rowpair, 5 grp); block 256 = 4 waves, wave w does ic chunks 4w..4w+3
__global__ __launch_bounds__(256) void conv3x3_all(
    const unsigned short* __restrict__ xT_h,  // [30][16][1024][16]
    const unsigned short* __restrict__ xT_l,
    const short* __restrict__ wp_hi_all,      // [6][9][160][256]
    const short* __restrict__ wp_lo_all,
    const float* __restrict__ biasc_all,      // [6][160]
    unsigned short* __restrict__ kt_hi, unsigned short* __restrict__ kt_lo, // [20][1024][32]
    unsigned short* __restrict__ vt,                                         // [20][128][1024]
    unsigned short* __restrict__ kq_hi, unsigned short* __restrict__ kq_lo, // [10][1024][32]
    unsigned short* __restrict__ vq)                                         // [10][128][1024]
{
    __shared__ float s_red[4][2][16][64];     // 32 KB
    const int tid = threadIdx.x;
    const int img = blockIdx.x;
    const int yp  = blockIdx.y;
    const int grp = blockIdx.z;
    const bool iskey = (grp == 0);
    const int set = (img < 20) ? 0 : 1 + ((img - 20) >> 1);
    const int ocb = grp * 32;
    const int wave = tid >> 6, lane = tid & 63, l31 = tid & 31, lh = (tid >> 5) & 1;
    const int y0 = yp * 2;

    f32x16 acc0 = {}, acc1 = {};
    const bf16x8 bz = {};
    const unsigned short* xh = xT_h + (size_t)img * 16 * 16384;
    const unsigned short* xl = xT_l + (size_t)img * 16 * 16384;
    const short* wph = wp_hi_all + (size_t)set * 368640;
    const short* wpl = wp_lo_all + (size_t)set * 368640;
    const float* bset = biasc_all + set * 160;

    for (int cc = 0; cc < 4; ++cc) {
        const int ch = (wave << 2) + cc;
        const unsigned short* xhc = xh + (size_t)ch * 16384 + lh * 8;
        const unsigned short* xlc = xl + (size_t)ch * 16384 + lh * 8;
#pragma unroll
        for (int tg = 0; tg < 3; ++tg) {
            bf16x8 wh[3], wl[3];
#pragma unroll
            for (int tl = 0; tl < 3; ++tl) {
                size_t wi = ((size_t)((tg * 3 + tl) * 160 + ocb + l31)) * 256 + (ch << 4) + lh * 8;
                wh[tl] = *(const bf16x8*)&wph[wi];
                if (iskey) wl[tl] = *(const bf16x8*)&wpl[wi];
            }
#pragma unroll
            for (int nt = 0; nt < 2; ++nt) {
                const int ri = y0 + nt - 1 + tg;
                const bool rok = (ri >= 0 && ri < 32);
#pragma unroll
                for (int tl = 0; tl < 3; ++tl) {
                    const int x = l31 + tl - 1;
                    const bool ok = rok && (x >= 0) && (x < 32);
                    bf16x8 bh = bz, bl = bz;
                    if (ok) {
                        const int p = ri * 32 + x;
                        bh = *(const bf16x8*)&xhc[p * 16];
                        if (iskey) bl = *(const bf16x8*)&xlc[p * 16];
                    }
                    f32x16& a = nt ? acc1 : acc0;
                    a = __builtin_amdgcn_mfma_f32_32x32x16_bf16(wh[tl], bh, a, 0, 0, 0);
                    if (iskey) {
                        a = __builtin_amdgcn_mfma_f32_32x32x16_bf16(wh[tl], bl, a, 0, 0, 0);
                        a = __builtin_amdgcn_mfma_f32_32x32x16_bf16(wl[tl], bh, a, 0, 0, 0);
                    }
                }
            }
        }
    }
    // cross-wave ic reduce through LDS
#pragma unroll
    for (int r = 0; r < 16; ++r) {
        s_red[wave][0][r][lane] = acc0[r];
        s_red[wave][1][r][lane] = acc1[r];
    }
    __syncthreads();
    float r0[4], r1[4];
#pragma unroll
    for (int j = 0; j < 4; ++j) {
        int r = (wave << 2) + j;
        r0[j] = s_red[0][0][r][lane] + s_red[1][0][r][lane] + s_red[2][0][r][lane] + s_red[3][0][r][lane];
        r1[j] = s_red[0][1][r][lane] + s_red[1][1][r][lane] + s_red[2][1][r][lane] + s_red[3][1][r][lane];
    }
    // epilogue: wave w owns the r-quad qd = w (reg r = 4*w + j -> row j + 8*w + 4*lh)
    if (iskey) {
#pragma unroll
        for (int nt = 0; nt < 2; ++nt) {
            const float* rr = nt ? r1 : r0;
            int p = (y0 + nt) * 32 + l31;
            int ocq = 8 * wave + 4 * lh;
            us4 h4, l4;
#pragma unroll
            for (int j = 0; j < 4; ++j) {
                unsigned short h, l;
                bf16split(rr[j] + bset[ocq + j], h, l);
                h4[j] = h; l4[j] = l;
            }
            if (img < 20) {
                size_t base = ((size_t)img * 1024 + p) * 32;
                *(us4*)&kt_hi[base + ocq] = h4;
                *(us4*)&kt_lo[base + ocq] = l4;
            } else {
                size_t base = ((size_t)(img - 20) * 1024 + p) * 32;
                *(us4*)&kq_hi[base + ocq] = h4;
                *(us4*)&kq_lo[base + ocq] = l4;
            }
        }
    } else {
#pragma unroll
        for (int nt = 0; nt < 2; ++nt) {
            const float* rr = nt ? r1 : r0;
            int p = (y0 + nt) * 32 + l31;
#pragma unroll
            for (int j = 0; j < 4; ++j) {
                int pat = j + 8 * wave + 4 * lh;
                int vo = (ocb - 32) + pat;
                unsigned short val = f2bf(rr[j] + bset[32 + vo]);
                if (img < 20) vt[((size_t)img * 128 + vo) * 1024 + p] = val;
                else          vq[((size_t)(img - 20) * 128 + vo) * 1024 + p] = val;
            }
        }
    }
}

// ---------------- flash relation-attention v4: NO LDS, NO barriers ----------------
// grid (16 t-tiles of 64, 2 b, 20 n), block 256 = 4 waves: tw = w&1 (t-half), vw = w>>1 (v-half)
// V fragments are loaded DIRECTLY from global (vq/vt slices are L2-resident).
__global__ __launch_bounds__(256, 2) void flash4(
    const unsigned short* __restrict__ kt_hi, const unsigned short* __restrict__ kt_lo,
    const unsigned short* __restrict__ vt_bf,
    const unsigned short* __restrict__ kq_hi, const unsigned short* __restrict__ kq_lo,
    const unsigned short* __restrict__ vq_bf,
    unsigned short* __restrict__ fin_part)   // [20][2][256][1024] bf16
{
    const int tid = threadIdx.x;
    const int t0 = blockIdx.x * 64;
    const int b  = blockIdx.y;
    const int n  = blockIdx.z;
    const int wave = tid >> 6, lane = tid & 63, l31 = lane & 31, lh = lane >> 5;
    const int tw = wave & 1, vw = wave >> 1;

    // hoisted key_t B-fragments (constant for the whole q loop)
    const int trow = t0 + tw * 32 + l31;
    bf16x8 btk_h0, btk_h1, btk_l0, btk_l1;
    {
        size_t g = ((size_t)n * 1024 + trow) * 32 + lh * 8;
        btk_h0 = *(const bf16x8*)&kt_hi[g];
        btk_h1 = *(const bf16x8*)&kt_hi[g + 16];
        btk_l0 = *(const bf16x8*)&kt_lo[g];
        btk_l1 = *(const bf16x8*)&kt_lo[g + 16];
    }

    // this wave's V row pointers (A-operand rows): vw=0 -> vq[b] rows 0..127, vw=1 -> vt[n]
    const unsigned short* vbase = (vw == 0)
        ? (vq_bf + (size_t)b * 131072)
        : (vt_bf + (size_t)n * 131072);
    const unsigned short* vrow[4];
#pragma unroll
    for (int vs = 0; vs < 4; ++vs)
        vrow[vs] = vbase + ((size_t)(vs * 32 + l31)) * 1024 + lh * 8;

    const unsigned short* kqh = kq_hi + (size_t)b * 1024 * 32;
    const unsigned short* kql = kq_lo + (size_t)b * 1024 * 32;

    // prefetch q0 = 0
    bf16x8 nva[4][2];
#pragma unroll
    for (int vs = 0; vs < 4; ++vs) {
        nva[vs][0] = *(const bf16x8*)&vrow[vs][0];
        nva[vs][1] = *(const bf16x8*)&vrow[vs][16];
    }
    bf16x8 nah0 = *(const bf16x8*)&kqh[(size_t)l31 * 32 + lh * 8];
    bf16x8 nah1 = *(const bf16x8*)&kqh[(size_t)l31 * 32 + 16 + lh * 8];
    bf16x8 nal0 = *(const bf16x8*)&kql[(size_t)l31 * 32 + lh * 8];
    bf16x8 nal1 = *(const bf16x8*)&kql[(size_t)l31 * 32 + 16 + lh * 8];

    f32x16 acc0 = {}, acc1 = {}, acc2 = {}, acc3 = {};
    float m = -3.0e38f, lsum = 0.f;

    for (int q0 = 0; q0 < 1024; q0 += 32) {
        // current-step operands from prefetch regs
        bf16x8 va[4][2];
#pragma unroll
        for (int vs = 0; vs < 4; ++vs) { va[vs][0] = nva[vs][0]; va[vs][1] = nva[vs][1]; }
        bf16x8 ah0 = nah0, ah1 = nah1, al0 = nal0, al1 = nal1;

        if (q0 + 32 < 1024) {   // issue next-step loads (overlap with compute; no barrier to drain them)
            const int qn = q0 + 32;
#pragma unroll
            for (int vs = 0; vs < 4; ++vs) {
                nva[vs][0] = *(const bf16x8*)&vrow[vs][qn];
                nva[vs][1] = *(const bf16x8*)&vrow[vs][qn + 16];
            }
            size_t kb = (size_t)(qn + l31) * 32 + lh * 8;
            nah0 = *(const bf16x8*)&kqh[kb];
            nah1 = *(const bf16x8*)&kqh[kb + 16];
            nal0 = *(const bf16x8*)&kql[kb];
            nal1 = *(const bf16x8*)&kql[kb + 16];
        }

        // S tile [32 q][32 t] in log2 domain (kq pre-scaled by log2 e)
        f32x16 s = {};
        s = __builtin_amdgcn_mfma_f32_32x32x16_bf16(ah0, btk_h0, s, 0, 0, 0);
        s = __builtin_amdgcn_mfma_f32_32x32x16_bf16(ah0, btk_l0, s, 0, 0, 0);
        s = __builtin_amdgcn_mfma_f32_32x32x16_bf16(al0, btk_h0, s, 0, 0, 0);
        s = __builtin_amdgcn_mfma_f32_32x32x16_bf16(ah1, btk_h1, s, 0, 0, 0);
        s = __builtin_amdgcn_mfma_f32_32x32x16_bf16(ah1, btk_l1, s, 0, 0, 0);
        s = __builtin_amdgcn_mfma_f32_32x32x16_bf16(al1, btk_h1, s, 0, 0, 0);

        // online softmax over q (lane holds one t-column, 16 q rows; partner lane has other 16)
        float pmax = s[0];
#pragma unroll
        for (int r = 1; r < 16; ++r) pmax = fmaxf(pmax, s[r]);
        pmax = fmaxf(pmax, __shfl_xor(pmax, 32));
        if (!__all(pmax <= m + 11.5417f)) {   // defer-max, THR = 8 nats in log2
            float mnew = fmaxf(m, pmax);
            float sc = __builtin_amdgcn_exp2f(m - mnew);
            m = mnew; lsum *= sc;
            acc0 *= sc; acc1 *= sc; acc2 *= sc; acc3 *= sc;
        }
        float pv[16]; float ps = 0.f;
#pragma unroll
        for (int r = 0; r < 16; ++r) { pv[r] = __builtin_amdgcn_exp2f(s[r] - m); ps += pv[r]; }
        lsum += ps;   // lane-partial; merged with partner at epilogue

        // P -> B-operand frags (in-register: cvt_pk + permlane32_swap)
        unsigned a0, a1, a2, a3, c0, c1, c2, c3;
        asm("v_cvt_pk_bf16_f32 %0, %1, %2" : "=v"(a0) : "v"(pv[0]),  "v"(pv[1]));
        asm("v_cvt_pk_bf16_f32 %0, %1, %2" : "=v"(a1) : "v"(pv[2]),  "v"(pv[3]));
        asm("v_cvt_pk_bf16_f32 %0, %1, %2" : "=v"(a2) : "v"(pv[4]),  "v"(pv[5]));
        asm("v_cvt_pk_bf16_f32 %0, %1, %2" : "=v"(a3) : "v"(pv[6]),  "v"(pv[7]));
        asm("v_cvt_pk_bf16_f32 %0, %1, %2" : "=v"(c0) : "v"(pv[8]),  "v"(pv[9]));
        asm("v_cvt_pk_bf16_f32 %0, %1, %2" : "=v"(c1) : "v"(pv[10]), "v"(pv[11]));
        asm("v_cvt_pk_bf16_f32 %0, %1, %2" : "=v"(c2) : "v"(pv[12]), "v"(pv[13]));
        asm("v_cvt_pk_bf16_f32 %0, %1, %2" : "=v"(c3) : "v"(pv[14]), "v"(pv[15]));
        asm("v_permlane32_swap_b32 %0, %1" : "+v"(a0), "+v"(a2));
        asm("v_permlane32_swap_b32 %0, %1" : "+v"(a1), "+v"(a3));
        asm("v_permlane32_swap_b32 %0, %1" : "+v"(c0), "+v"(c2));
        asm("v_permlane32_swap_b32 %0, %1" : "+v"(c1), "+v"(c3));
        union { unsigned u[4]; bf16x8 v; } f0, f1;
        f0.u[0] = a0; f0.u[1] = a1; f0.u[2] = a2; f0.u[3] = a3;
        f1.u[0] = c0; f1.u[1] = c1; f1.u[2] = c2; f1.u[3] = c3;

        // PV: this wave's v-half, A-operands straight from prefetch registers
#pragma unroll
        for (int vs = 0; vs < 4; ++vs) {
            f32x16& a = (vs == 0) ? acc0 : (vs == 1) ? acc1 : (vs == 2) ? acc2 : acc3;
            a = __builtin_amdgcn_mfma_f32_32x32x16_bf16(va[vs][0], f0.v, a, 0, 0, 0);
            a = __builtin_amdgcn_mfma_f32_32x32x16_bf16(va[vs][1], f1.v, a, 0, 0, 0);
        }
    }

    float lt = lsum + __shfl_xor(lsum, 32);
    float linv = 1.f / lt;
    unsigned short* outp = fin_part + ((size_t)(n * 2 + b)) * 256 * 1024;
    const int tg = t0 + tw * 32 + l31;
#pragma unroll
    for (int vs = 0; vs < 4; ++vs) {
        const f32x16& a = (vs == 0) ? acc0 : (vs == 1) ? acc1 : (vs == 2) ? acc2 : acc3;
#pragma unroll
        for (int r = 0; r < 16; ++r) {
            int v = vw * 128 + vs * 32 + (r & 3) + 8 * (r >> 2) + 4 * lh;
            outp[(size_t)v * 1024 + tg] = f2bf(a[r] * linv);
        }
    }
}

// ---------------- sum 20 bf16 n-slabs -> bf16 fsm slice ----------------
__global__ __launch_bounds__(256) void reduce20_bf(
    const unsigned short* __restrict__ part, unsigned short* __restrict__ out)
{
    size_t i = (size_t)blockIdx.x * 256 + threadIdx.x;
    float s = 0.f;
#pragma unroll
    for (int nn = 0; nn < 20; ++nn) s += bf2f(part[(size_t)nn * 524288 + i]);
    out[i] = f2bf(s);
}

// ---------------- bilinear upsample 32x32 -> HxH, bf16 in / fp32 out ----------------
__global__ __launch_bounds__(256) void upsample_bf(
    const unsigned short* __restrict__ in,   // level slice [2][256][1024] bf16
    float* __restrict__ out,                 // [2][256][H][H] fp32
    int oh, int ow, int total)
{
    int idx = blockIdx.x * 256 + threadIdx.x;
    if (idx >= total) return;
    int x  = idx % ow;
    int y  = (idx / ow) % oh;
    int bc = idx / (ow * oh);
    float fy = (float)y * 31.0f / (float)(oh - 1);
    float fx = (float)x * 31.0f / (float)(ow - 1);
    int y0 = (int)fy; int y1 = min(y0 + 1, 31); float wy = fy - (float)y0;
    int x0 = (int)fx; int x1 = min(x0 + 1, 31); float wx = fx - (float)x0;
    const unsigned short* p = in + (size_t)bc * 1024;
    float a = bf2f(p[y0 * 32 + x0]), b = bf2f(p[y1 * 32 + x0]);
    float c = bf2f(p[y0 * 32 + x1]), d = bf2f(p[y1 * 32 + x1]);
    float c0 = a + (b - a) * wy;
    float c1 = c + (d - c) * wy;
    out[idx] = c0 + (c1 - c0) * wx;
}

// ---------------- BN stats over (b, spatial) per channel ----------------
__global__ __launch_bounds__(256) void bnstats_kernel(
    const float* __restrict__ fin, float* __restrict__ mu, float* __restrict__ var, int HW)
{
    const int c = blockIdx.x;
    float s = 0.f, s2 = 0.f;
    for (int b = 0; b < 2; ++b) {
        const float* p = fin + ((size_t)b * 256 + c) * HW;
        for (int i = threadIdx.x; i < HW; i += 256) {
            float v = p[i]; s += v; s2 += v * v;
        }
    }
#pragma unroll
    for (int off = 32; off; off >>= 1) {
        s  += __shfl_xor(s, off);
        s2 += __shfl_xor(s2, off);
    }
    __shared__ float r1[4], r2[4];
    if ((threadIdx.x & 63) == 0) { r1[threadIdx.x >> 6] = s; r2[threadIdx.x >> 6] = s2; }
    __syncthreads();
    if (threadIdx.x == 0) {
        float cnt = 2.f * (float)HW;
        float mm = (r1[0] + r1[1] + r1[2] + r1[3]) / cnt;
        float qq = (r2[0] + r2[1] + r2[2] + r2[3]) / cnt;
        mu[c] = mm; var[c] = qq - mm * mm;
    }
}

// ---------------- fold BN into comb weights ----------------
__global__ __launch_bounds__(256) void prep_comb(
    const float* __restrict__ comb_w, const float* __restrict__ comb_b,
    const float* __restrict__ gamma, const float* __restrict__ beta,
    const float* __restrict__ mu, const float* __restrict__ var,
    short* __restrict__ wc, float* __restrict__ bias2)
{
    const int oc = blockIdx.x;
    const int ic = threadIdx.x;
    float a  = gamma[ic] * rsqrtf(var[ic] + 1e-5f);
    float bb = beta[ic] - mu[ic] * a;
    float w1 = comb_w[(size_t)oc * 512 + ic];
    float w2 = comb_w[(size_t)oc * 512 + 256 + ic];
    wc[(size_t)oc * 512 + ic]       = (short)f2bf(w1);
    wc[(size_t)oc * 512 + 256 + ic] = (short)f2bf(w2 * a);
    float s = w2 * bb;
#pragma unroll
    for (int off = 32; off; off >>= 1) s += __shfl_xor(s, off);
    __shared__ float red[4];
    if ((threadIdx.x & 63) == 0) red[threadIdx.x >> 6] = s;
    __syncthreads();
    if (threadIdx.x == 0)
        bias2[oc] = comb_b[oc] + red[0] + red[1] + red[2] + red[3];
}

// ---------------- comb 1x1 conv as MFMA GEMM (fp32 fin) ----------------
__global__ __launch_bounds__(256, 1) void comb_mfma(
    const float* __restrict__ f,    // [2][256][HW]
    const float* __restrict__ fin,  // [2][256][HW] fp32
    const short* __restrict__ wc,   // [256][512] bf16
    const float* __restrict__ bias2,
    float* __restrict__ out, int HW)
{
    __shared__ short s_wc[256 * 40];
    __shared__ short s_xc[128 * 40];
    const int tid = threadIdx.x;
    const int p0 = blockIdx.x * 128;
    const int b  = blockIdx.y;
    const int wv = tid >> 6, l31 = tid & 31, lh = (tid >> 5) & 1;
    const int wm = wv >> 1, wn = wv & 1;

    f32x16 acc[4][2];
#pragma unroll
    for (int i = 0; i < 4; ++i)
#pragma unroll
        for (int j = 0; j < 2; ++j)
#pragma unroll
            for (int r = 0; r < 16; ++r) acc[i][j][r] = 0.f;

    for (int k0 = 0; k0 < 512; k0 += 32) {
        __syncthreads();
        for (int u = tid; u < 512; u += 256) {
            int r = u >> 1, h = u & 1;
            *(bf16x8*)&s_wc[r * 40 + h * 16 + 0] = *(const bf16x8*)&wc[(size_t)r * 512 + k0 + h * 16];
            *(bf16x8*)&s_wc[r * 40 + h * 16 + 8] = *(const bf16x8*)&wc[(size_t)r * 512 + k0 + h * 16 + 8];
        }
        for (int u = tid; u < 1024; u += 256) {
            int kr = u >> 5, n4 = (u & 31) * 4;
            int ck = k0 + kr;
            const float* bsrc = (ck < 256)
                ? f   + ((size_t)(b * 256 + ck)) * HW
                : fin + ((size_t)(b * 256 + ck - 256)) * HW;
            int p = p0 + n4;
            float v0, v1, v2, v3;
            if (p + 3 < HW) {
                float4 v4 = *(const float4*)&bsrc[p];
                v0 = v4.x; v1 = v4.y; v2 = v4.z; v3 = v4.w;
            } else {
                v0 = bsrc[min(p,     HW - 1)];
                v1 = bsrc[min(p + 1, HW - 1)];
                v2 = bsrc[min(p + 2, HW - 1)];
                v3 = bsrc[min(p + 3, HW - 1)];
            }
            s_xc[(n4 + 0) * 40 + kr] = (short)f2bf(v0);
            s_xc[(n4 + 1) * 40 + kr] = (short)f2bf(v1);
            s_xc[(n4 + 2) * 40 + kr] = (short)f2bf(v2);
            s_xc[(n4 + 3) * 40 + kr] = (short)f2bf(v3);
        }
        __syncthreads();
#pragma unroll
        for (int ks = 0; ks < 2; ++ks) {
            bf16x8 a[4], bx[2];
#pragma unroll
            for (int mi = 0; mi < 4; ++mi)
                a[mi] = *(const bf16x8*)&s_wc[(wm * 128 + mi * 32 + l31) * 40 + ks * 16 + lh * 8];
#pragma unroll
            for (int ni = 0; ni < 2; ++ni)
                bx[ni] = *(const bf16x8*)&s_xc[(wn * 64 + ni * 32 + l31) * 40 + ks * 16 + lh * 8];
#pragma unroll
            for (int mi = 0; mi < 4; ++mi)
#pragma unroll
                for (int ni = 0; ni < 2; ++ni)
                    acc[mi][ni] = __builtin_amdgcn_mfma_f32_32x32x16_bf16(a[mi], bx[ni], acc[mi][ni], 0, 0, 0);
        }
    }
#pragma unroll
    for (int mi = 0; mi < 4; ++mi) {
#pragma unroll
        for (int ni = 0; ni < 2; ++ni) {
            int p = p0 + wn * 64 + ni * 32 + l31;
            if (p < HW) {
#pragma unroll
                for (int r = 0; r < 16; ++r) {
                    int oc = wm * 128 + mi * 32 + (r & 3) + 8 * (r >> 2) + 4 * lh;
                    out[((size_t)(b * 256 + oc)) * HW + p] = acc[mi][ni][r] + bias2[oc];
                }
            }
        }
    }
}

// ---------------- host orchestration ----------------
extern "C" void kernel_launch(void* const* d_in, const int* in_sizes, int n_in,
                              void* d_out, int out_size, void* d_ws, size_t ws_size,
                              hipStream_t stream) {
    if (ws_size < WS_BYTES) return;

    const float* feats[5];
    for (int i = 0; i < 5; ++i) feats[i] = (const float*)d_in[i];
    const float* attn     = (const float*)d_in[5];
    const float* key_t_w  = (const float*)d_in[6];
    const float* key_t_b  = (const float*)d_in[7];
    const float* val_t_w  = (const float*)d_in[8];
    const float* val_t_b  = (const float*)d_in[9];
    const float* key_q_w  = (const float*)d_in[10];
    const float* key_q_b  = (const float*)d_in[11];
    const float* val_q_w  = (const float*)d_in[12];
    const float* val_q_b  = (const float*)d_in[13];
    const float* bn_gamma = (const float*)d_in[14];
    const float* bn_beta  = (const float*)d_in[15];
    const float* comb_w   = (const float*)d_in[16];
    const float* comb_b   = (const float*)d_in[17];

    char* ws = (char*)d_ws;
    float* biasc = (float*)(ws + B_BIASC);
    unsigned short* kt_hi = (unsigned short*)(ws + B_KTH);
    unsigned short* kt_lo = (unsigned short*)(ws + B_KTL);
    unsigned short* vt    = (unsigned short*)(ws + B_VT);
    unsigned short* kq_hi = (unsigned short*)(ws + B_KQH);
    unsigned short* kq_lo = (unsigned short*)(ws + B_KQL);
    unsigned short* vq    = (unsigned short*)(ws + B_VQ);
    float* mean_f = (float*)(ws + B_MEAN);
    unsigned short* fsm = (unsigned short*)(ws + B_FSM);
    float* mu     = (float*)(ws + B_MU);
    float* var    = (float*)(ws + B_VAR);
    short* wc_bf  = (short*)(ws + B_WC);
    float* bias2  = (float*)(ws + B_BIAS2);
    unsigned short* X_h = (unsigned short*)(ws + B_UNION + U_XH);
    unsigned short* X_l = (unsigned short*)(ws + B_UNION + U_XL);
    short* wp_hi = (short*)(ws + B_UNION + U_WPH);
    short* wp_lo = (short*)(ws + B_UNION + U_WPL);
    unsigned short* fin_part = (unsigned short*)(ws + B_UNION + U_FPART);
    float* fin_big = (float*)(ws + B_UNION);   // overwrites fin_part after reduce20

    prep_weights<<<dim3(160, 6), 256, 0, stream>>>(
        key_t_w, key_t_b, val_t_w, val_t_b, key_q_w, key_q_b, val_q_w, val_q_b,
        wp_hi, wp_lo, biasc);

    transpose_split<<<dim3(20, 16, 4), 256, 0, stream>>>(attn, X_h, X_l);

    mean2d_all<<<dim3(512, 5), 256, 0, stream>>>(
        feats[0], feats[1], feats[2], feats[3], feats[4], mean_f);

    resizeT_all<<<dim3(2, 16, 20), 256, 0, stream>>>(
        feats[0], feats[1], feats[2], feats[3], feats[4], mean_f, X_h, X_l);

    conv3x3_all<<<dim3(30, 16, 5), 256, 0, stream>>>(
        X_h, X_l, wp_hi, wp_lo, biasc, kt_hi, kt_lo, vt, kq_hi, kq_lo, vq);

    size_t out_off = 0;
    for (int idx = 0; idx < 5; ++idx) {
        const int H = 128 >> idx, HW = H * H;
        const int total = 2 * 256 * HW;

        flash4<<<dim3(16, 2, 20), 256, 0, stream>>>(
            kt_hi, kt_lo, vt,
            kq_hi + (size_t)idx * 2 * 32768,
            kq_lo + (size_t)idx * 2 * 32768,
            vq + (size_t)idx * 2 * 131072,
            fin_part);

        reduce20_bf<<<2048, 256, 0, stream>>>(fin_part, fsm + (size_t)idx * 524288);

        upsample_bf<<<(total + 255) / 256, 256, 0, stream>>>(
            fsm + (size_t)idx * 524288, fin_big, H, H, total);

        bnstats_kernel<<<256, 256, 0, stream>>>(fin_big, mu + idx * 256, var + idx * 256, HW);

        prep_comb<<<256, 256, 0, stream>>>(
            comb_w, comb_b, bn_gamma + idx * 256, bn_beta + idx * 256,
            mu + idx * 256, var + idx * 256, wc_bf + (size_t)idx * 131072, bias2 + idx * 256);

        comb_mfma<<<dim3((HW + 127) / 128, 2), 256, 0, stream>>>(
            feats[idx], fin_big, wc_bf + (size_t)idx * 131072, bias2 + idx * 256,
            (float*)d_out + out_off, HW);

        out_off += (size_t)2 * 256 * HW;
    }
}

// Round 11
// 1058.321 us; speedup vs baseline: 1.0233x; 1.0233x over previous
//
#include <hip/hip_runtime.h>
#include <cstddef>
#include <cstdint>

typedef __attribute__((ext_vector_type(8))) short bf16x8;
typedef __attribute__((ext_vector_type(16))) float f32x16;
typedef __attribute__((ext_vector_type(4))) unsigned short us4;

// ---------------- workspace layout (byte offsets) ----------------
static const size_t B_BIASC = 0;            // 6*160*4 = 3,840
static const size_t B_KTH   = 3840;         // 20*1024*32*2 = 1,310,720
static const size_t B_KTL   = 1314560;      // 1,310,720
static const size_t B_VT    = 2625280;      // 20*128*1024*2 = 5,242,880
static const size_t B_KQH   = 7868160;      // 5*2*1024*32*2 = 655,360
static const size_t B_KQL   = 8523520;      // 655,360
static const size_t B_VQ    = 9178880;      // 5*2*128*1024*2 = 2,621,440
static const size_t B_MEAN  = 11800320;     // 5*512*4 = 10,240
static const size_t B_FSM   = 11810560;     // 5*2*256*1024*2 = 5,242,880 (bf16)
static const size_t B_MU    = 17053440;     // 5*256*4 = 5,120
static const size_t B_VAR   = 17058560;     // 5,120
static const size_t B_WC    = 17063680;     // 5*256*512*2 = 1,310,720
static const size_t B_BIAS2 = 18374400;     // 5,120
static const size_t B_UNION = 18379520;     // 41,943,040 union region
// phase 1: X_all_hi +0 (15,728,640), X_all_lo +15,728,640, wp_hi +31,457,280, wp_lo +35,880,960
// phase 2 (per level): part2 +0 (2*20*2*256*1024*2 = 41,943,040) -> reduce40 -> fsm;
//                      then fin_big fp32 +0 (<=33,554,432) overwrites it
static const size_t U_XH    = 0;
static const size_t U_XL    = 15728640;
static const size_t U_WPH   = 31457280;
static const size_t U_WPL   = 35880960;
static const size_t U_FPART = 0;
static const size_t B_ML    = 60322560;     // 2*20*2*1024*8 = 655,360 (float2 m,l)
static const size_t WS_BYTES = 60977920;    // ~61.0 MB (<= 61,084,672 proven round 1)

// ---------------- bf16 helpers (RNE) ----------------
__device__ inline unsigned short f2bf(float x) {
    unsigned u = __float_as_uint(x);
    return (unsigned short)((u + 0x7fffu + ((u >> 16) & 1u)) >> 16);
}
__device__ inline float bf2f(unsigned short u) {
    return __uint_as_float(((unsigned)u) << 16);
}
__device__ inline void bf16split(float x, unsigned short& hi, unsigned short& lo) {
    unsigned u = __float_as_uint(x);
    unsigned hb = (u + 0x7fffu + ((u >> 16) & 1u)) >> 16;
    hi = (unsigned short)hb;
    float hf = __uint_as_float(hb << 16);
    float r = x - hf;
    unsigned ur = __float_as_uint(r);
    lo = (unsigned short)((ur + 0x7fffu + ((ur >> 16) & 1u)) >> 16);
}
__device__ inline const float* sel5(const float* a, const float* b, const float* c,
                                    const float* d, const float* e, int i) {
    return i == 0 ? a : i == 1 ? b : i == 2 ? c : i == 3 ? d : e;
}

// ---------------- weight pre-transform ----------------
__global__ __launch_bounds__(256) void prep_weights(
    const float* __restrict__ kt_w, const float* __restrict__ kt_b,
    const float* __restrict__ vt_w, const float* __restrict__ vt_b,
    const float* __restrict__ kq_w, const float* __restrict__ kq_b,
    const float* __restrict__ vq_w, const float* __restrict__ vq_b,
    short* __restrict__ wp_hi, short* __restrict__ wp_lo, float* __restrict__ biasc)
{
    const int oc = blockIdx.x;    // 0..159
    const int s  = blockIdx.y;    // 0..5 (0 = stage A, 1+idx = level)
    const int ic = threadIdx.x;   // 0..255
    const bool iskey = oc < 32;
    const int ocl = iskey ? oc : oc - 32;
    const float scale = (iskey && s > 0) ? 1.4426950408889634f : 1.0f;
    const float* w = iskey
        ? (s == 0 ? kt_w : kq_w + (size_t)(s - 1) * 32 * 256 * 9)
        : (s == 0 ? vt_w : vq_w + (size_t)(s - 1) * 128 * 256 * 9);
    const float* wsrc = w + ((size_t)ocl * 256 + ic) * 9;
#pragma unroll
    for (int t = 0; t < 9; ++t) {
        unsigned short h, l; bf16split(wsrc[t] * scale, h, l);
        size_t d = ((size_t)(s * 9 + t) * 160 + oc) * 256 + ic;
        wp_hi[d] = (short)h; wp_lo[d] = (short)l;
    }
    if (ic == 0) {
        const float* bptr = iskey
            ? (s == 0 ? kt_b : kq_b + (s - 1) * 32)
            : (s == 0 ? vt_b : vq_b + (s - 1) * 128);
        biasc[s * 160 + oc] = bptr[ocl] * scale;
    }
}

// ---------------- fp32 [20][256][1024] -> bf16 hi/lo X_all imgs 0..19 ----------------
__global__ __launch_bounds__(256) void transpose_split(
    const float* __restrict__ in,
    unsigned short* __restrict__ oh, unsigned short* __restrict__ ol)
{
    __shared__ float s[16][260];
    const int n = blockIdx.x, ch = blockIdx.y, p0 = blockIdx.z * 256;
    const int tid = threadIdx.x;
#pragma unroll
    for (int i = 0; i < 16; ++i)
        s[i][tid] = in[((size_t)(n * 256 + ch * 16 + i)) * 1024 + p0 + tid];
    __syncthreads();
    union { unsigned short u[16]; bf16x8 v[2]; } h8, l8;
#pragma unroll
    for (int i = 0; i < 16; ++i) bf16split(s[i][tid], h8.u[i], l8.u[i]);
    size_t base = ((size_t)(n * 16 + ch) * 1024 + p0 + tid) * 16;
    *(bf16x8*)&oh[base] = h8.v[0]; *(bf16x8*)&oh[base + 8] = h8.v[1];
    *(bf16x8*)&ol[base] = l8.v[0]; *(bf16x8*)&ol[base + 8] = l8.v[1];
}

// ---------------- batched per (lvl,b,c) spatial mean ----------------
__global__ __launch_bounds__(256) void mean2d_all(
    const float* f0, const float* f1, const float* f2, const float* f3, const float* f4,
    float* __restrict__ mean)
{
    const int lvl = blockIdx.y;
    const float* f = sel5(f0, f1, f2, f3, f4, lvl);
    const int H = 128 >> lvl, HW = H * H;
    const int bc = blockIdx.x;
    const float* src = f + (size_t)bc * HW;
    float s = 0.f;
    for (int i = threadIdx.x; i < HW; i += 256) s += src[i];
#pragma unroll
    for (int off = 32; off; off >>= 1) s += __shfl_xor(s, off);
    __shared__ float red[4];
    if ((threadIdx.x & 63) == 0) red[threadIdx.x >> 6] = s;
    __syncthreads();
    if (threadIdx.x == 0)
        mean[lvl * 512 + bc] = (red[0] + red[1] + red[2] + red[3]) / (float)HW;
}

// ---------------- batched resize (HxH->32x32) + mean-sub -> X_all imgs 20..29 ----------------
__global__ __launch_bounds__(256) void resizeT_all(
    const float* f0, const float* f1, const float* f2, const float* f3, const float* f4,
    const float* __restrict__ mean,
    unsigned short* __restrict__ oh, unsigned short* __restrict__ ol)
{
    __shared__ float s[16][260];
    const int lvl = blockIdx.z >> 2;
    const int p0 = (blockIdx.z & 3) * 256;
    const int b = blockIdx.x, ch = blockIdx.y;
    const float* f = sel5(f0, f1, f2, f3, f4, lvl);
    const int H = 128 >> lvl;
    const int img = 20 + lvl * 2 + b;
    const int tid = threadIdx.x;
    const int p = p0 + tid, y = p >> 5, x = p & 31;
    float fy = (float)y * (float)(H - 1) / 31.0f;
    float fx = (float)x * (float)(H - 1) / 31.0f;
    int y0 = (int)fy; int y1 = min(y0 + 1, H - 1); float wy = fy - (float)y0;
    int x0 = (int)fx; int x1 = min(x0 + 1, H - 1); float wx = fx - (float)x0;
#pragma unroll
    for (int i = 0; i < 16; ++i) {
        int c = ch * 16 + i;
        const float* pf = f + ((size_t)(b * 256 + c)) * H * H;
        float a = pf[y0 * H + x0], bb = pf[y1 * H + x0];
        float cc = pf[y0 * H + x1], d = pf[y1 * H + x1];
        float c0 = a + (bb - a) * wy;
        float c1 = cc + (d - cc) * wy;
        s[i][tid] = c0 + (c1 - c0) * wx - mean[lvl * 512 + b * 256 + c];
    }
    __syncthreads();
    union { unsigned short u[16]; bf16x8 v[2]; } h8, l8;
#pragma unroll
    for (int i = 0; i < 16; ++i) bf16split(s[i][tid], h8.u[i], l8.u[i]);
    size_t base = ((size_t)(img * 16 + ch) * 1024 + p) * 16;
    *(bf16x8*)&oh[base] = h8.v[0]; *(bf16x8*)&oh[base + 8] = h8.v[1];
    *(bf16x8*)&ol[base] = l8.v[0]; *(bf16x8*)&ol[base + 8] = l8.v[1];
}

// ---------------- merged direct MFMA 3x3 conv: ic split across waves + LDS reduce ----------------
// grid (5 grp, 16 rowpair, 30 img) — grp fastest so the 5 blocks sharing X rows land on
// nearby XCDs back-to-back (L2 reuse). block 256 = 4 waves, wave w does ic chunks 4w..4w+3
__global__ __launch_bounds__(256) void conv3x3_all(
    const unsigned short* __restrict__ xT_h,  // [30][16][1024][16]
    const unsigned short* __restrict__ xT_l,
    const short* __restrict__ wp_hi_all,      // [6][9][160][256]
    const short* __restrict__ wp_lo_all,
    const float* __restrict__ biasc_all,      // [6][160]
    unsigned short* __restrict__ kt_hi, unsigned short* __restrict__ kt_lo, // [20][1024][32]
    unsigned short* __restrict__ vt,                                         // [20][128][1024]
    unsigned short* __restrict__ kq_hi, unsigned short* __restrict__ kq_lo, // [10][1024][32]
    unsigned short* __restrict__ vq)                                         // [10][128][1024]
{
    __shared__ float s_red[4][2][16][64];     // 32 KB
    const int tid = threadIdx.x;
    const int grp = blockIdx.x;
    const int yp  = blockIdx.y;
    const int img = blockIdx.z;
    const bool iskey = (grp == 0);
    const int set = (img < 20) ? 0 : 1 + ((img - 20) >> 1);
    const int ocb = grp * 32;
    const int wave = tid >> 6, lane = tid & 63, l31 = tid & 31, lh = (tid >> 5) & 1;
    const int y0 = yp * 2;

    f32x16 acc0 = {}, acc1 = {};
    const bf16x8 bz = {};
    const unsigned short* xh = xT_h + (size_t)img * 16 * 16384;
    const unsigned short* xl = xT_l + (size_t)img * 16 * 16384;
    const short* wph = wp_hi_all + (size_t)set * 368640;
    const short* wpl = wp_lo_all + (size_t)set * 368640;
    const float* bset = biasc_all + set * 160;

    for (int cc = 0; cc < 4; ++cc) {
        const int ch = (wave << 2) + cc;
        const unsigned short* xhc = xh + (size_t)ch * 16384 + lh * 8;
        const unsigned short* xlc = xl + (size_t)ch * 16384 + lh * 8;
#pragma unroll
        for (int tg = 0; tg < 3; ++tg) {
            bf16x8 wh[3], wl[3];
#pragma unroll
            for (int tl = 0; tl < 3; ++tl) {
                size_t wi = ((size_t)((tg * 3 + tl) * 160 + ocb + l31)) * 256 + (ch << 4) + lh * 8;
                wh[tl] = *(const bf16x8*)&wph[wi];
                if (iskey) wl[tl] = *(const bf16x8*)&wpl[wi];
            }
#pragma unroll
            for (int nt = 0; nt < 2; ++nt) {
                const int ri = y0 + nt - 1 + tg;
                const bool rok = (ri >= 0 && ri < 32);
#pragma unroll
                for (int tl = 0; tl < 3; ++tl) {
                    const int x = l31 + tl - 1;
                    const bool ok = rok && (x >= 0) && (x < 32);
                    bf16x8 bh = bz, bl = bz;
                    if (ok) {
                        const int p = ri * 32 + x;
                        bh = *(const bf16x8*)&xhc[p * 16];
                        if (iskey) bl = *(const bf16x8*)&xlc[p * 16];
                    }
                    f32x16& a = nt ? acc1 : acc0;
                    a = __builtin_amdgcn_mfma_f32_32x32x16_bf16(wh[tl], bh, a, 0, 0, 0);
                    if (iskey) {
                        a = __builtin_amdgcn_mfma_f32_32x32x16_bf16(wh[tl], bl, a, 0, 0, 0);
                        a = __builtin_amdgcn_mfma_f32_32x32x16_bf16(wl[tl], bh, a, 0, 0, 0);
                    }
                }
            }
        }
    }
    // cross-wave ic reduce through LDS
#pragma unroll
    for (int r = 0; r < 16; ++r) {
        s_red[wave][0][r][lane] = acc0[r];
        s_red[wave][1][r][lane] = acc1[r];
    }
    __syncthreads();
    float r0[4], r1[4];
#pragma unroll
    for (int j = 0; j < 4; ++j) {
        int r = (wave << 2) + j;
        r0[j] = s_red[0][0][r][lane] + s_red[1][0][r][lane] + s_red[2][0][r][lane] + s_red[3][0][r][lane];
        r1[j] = s_red[0][1][r][lane] + s_red[1][1][r][lane] + s_red[2][1][r][lane] + s_red[3][1][r][lane];
    }
    // epilogue: wave w owns the r-quad qd = w (reg r = 4*w + j -> row j + 8*w + 4*lh)
    if (iskey) {
#pragma unroll
        for (int nt = 0; nt < 2; ++nt) {
            const float* rr = nt ? r1 : r0;
            int p = (y0 + nt) * 32 + l31;
            int ocq = 8 * wave + 4 * lh;
            us4 h4, l4;
#pragma unroll
            for (int j = 0; j < 4; ++j) {
                unsigned short h, l;
                bf16split(rr[j] + bset[ocq + j], h, l);
                h4[j] = h; l4[j] = l;
            }
            if (img < 20) {
                size_t base = ((size_t)img * 1024 + p) * 32;
                *(us4*)&kt_hi[base + ocq] = h4;
                *(us4*)&kt_lo[base + ocq] = l4;
            } else {
                size_t base = ((size_t)(img - 20) * 1024 + p) * 32;
                *(us4*)&kq_hi[base + ocq] = h4;
                *(us4*)&kq_lo[base + ocq] = l4;
            }
        }
    } else {
#pragma unroll
        for (int nt = 0; nt < 2; ++nt) {
            const float* rr = nt ? r1 : r0;
            int p = (y0 + nt) * 32 + l31;
#pragma unroll
            for (int j = 0; j < 4; ++j) {
                int pat = j + 8 * wave + 4 * lh;
                int vo = (ocb - 32) + pat;
                unsigned short val = f2bf(rr[j] + bset[32 + vo]);
                if (img < 20) vt[((size_t)img * 128 + vo) * 1024 + p] = val;
                else          vq[((size_t)(img - 20) * 128 + vo) * 1024 + p] = val;
            }
        }
    }
}

// ---------------- flash relation-attention v5: no LDS/barriers + q-split x2 ----------------
// grid (16 t-tiles of 64, 2 b, 40 = n*2+qg), block 256 = 4 waves: tw = w&1, vw = w>>1
// Each block covers q in [qg*512, qg*512+512) (16 steps); writes weighted-mergeable
// partial output (acc/l) plus (m, l) per t-column into ml[].
__global__ __launch_bounds__(256, 2) void flash5(
    const unsigned short* __restrict__ kt_hi, const unsigned short* __restrict__ kt_lo,
    const unsigned short* __restrict__ vt_bf,
    const unsigned short* __restrict__ kq_hi, const unsigned short* __restrict__ kq_lo,
    const unsigned short* __restrict__ vq_bf,
    unsigned short* __restrict__ part2,      // [2 qg][20 n][2 b][256][1024] bf16
    float2* __restrict__ ml_out)             // [2 qg][20 n][2 b][1024] (m, l)
{
    const int tid = threadIdx.x;
    const int t0 = blockIdx.x * 64;
    const int b  = blockIdx.y;
    const int n  = blockIdx.z >> 1;
    const int qg = blockIdx.z & 1;
    const int qbase = qg * 512;
    const int wave = tid >> 6, lane = tid & 63, l31 = lane & 31, lh = lane >> 5;
    const int tw = wave & 1, vw = wave >> 1;

    // hoisted key_t B-fragments (constant for the whole q loop)
    const int trow = t0 + tw * 32 + l31;
    bf16x8 btk_h0, btk_h1, btk_l0, btk_l1;
    {
        size_t g = ((size_t)n * 1024 + trow) * 32 + lh * 8;
        btk_h0 = *(const bf16x8*)&kt_hi[g];
        btk_h1 = *(const bf16x8*)&kt_hi[g + 16];
        btk_l0 = *(const bf16x8*)&kt_lo[g];
        btk_l1 = *(const bf16x8*)&kt_lo[g + 16];
    }

    // this wave's V row pointers: vw=0 -> vq[b] rows 0..127, vw=1 -> vt[n]
    const unsigned short* vbase = (vw == 0)
        ? (vq_bf + (size_t)b * 131072)
        : (vt_bf + (size_t)n * 131072);
    const unsigned short* vrow[4];
#pragma unroll
    for (int vs = 0; vs < 4; ++vs)
        vrow[vs] = vbase + ((size_t)(vs * 32 + l31)) * 1024 + lh * 8;

    const unsigned short* kqh = kq_hi + (size_t)b * 1024 * 32;
    const unsigned short* kql = kq_lo + (size_t)b * 1024 * 32;

    // prefetch first step
    bf16x8 nva[4][2];
#pragma unroll
    for (int vs = 0; vs < 4; ++vs) {
        nva[vs][0] = *(const bf16x8*)&vrow[vs][qbase];
        nva[vs][1] = *(const bf16x8*)&vrow[vs][qbase + 16];
    }
    bf16x8 nah0 = *(const bf16x8*)&kqh[(size_t)(qbase + l31) * 32 + lh * 8];
    bf16x8 nah1 = *(const bf16x8*)&kqh[(size_t)(qbase + l31) * 32 + 16 + lh * 8];
    bf16x8 nal0 = *(const bf16x8*)&kql[(size_t)(qbase + l31) * 32 + lh * 8];
    bf16x8 nal1 = *(const bf16x8*)&kql[(size_t)(qbase + l31) * 32 + 16 + lh * 8];

    f32x16 acc0 = {}, acc1 = {}, acc2 = {}, acc3 = {};
    float m = -3.0e38f, lsum = 0.f;

    for (int q0 = qbase; q0 < qbase + 512; q0 += 32) {
        bf16x8 va[4][2];
#pragma unroll
        for (int vs = 0; vs < 4; ++vs) { va[vs][0] = nva[vs][0]; va[vs][1] = nva[vs][1]; }
        bf16x8 ah0 = nah0, ah1 = nah1, al0 = nal0, al1 = nal1;

        if (q0 + 32 < qbase + 512) {   // issue next-step loads (overlap with compute)
            const int qn = q0 + 32;
#pragma unroll
            for (int vs = 0; vs < 4; ++vs) {
                nva[vs][0] = *(const bf16x8*)&vrow[vs][qn];
                nva[vs][1] = *(const bf16x8*)&vrow[vs][qn + 16];
            }
            size_t kb = (size_t)(qn + l31) * 32 + lh * 8;
            nah0 = *(const bf16x8*)&kqh[kb];
            nah1 = *(const bf16x8*)&kqh[kb + 16];
            nal0 = *(const bf16x8*)&kql[kb];
            nal1 = *(const bf16x8*)&kql[kb + 16];
        }

        // S tile [32 q][32 t] in log2 domain (kq pre-scaled by log2 e)
        f32x16 s = {};
        __builtin_amdgcn_s_setprio(1);
        s = __builtin_amdgcn_mfma_f32_32x32x16_bf16(ah0, btk_h0, s, 0, 0, 0);
        s = __builtin_amdgcn_mfma_f32_32x32x16_bf16(ah0, btk_l0, s, 0, 0, 0);
        s = __builtin_amdgcn_mfma_f32_32x32x16_bf16(al0, btk_h0, s, 0, 0, 0);
        s = __builtin_amdgcn_mfma_f32_32x32x16_bf16(ah1, btk_h1, s, 0, 0, 0);
        s = __builtin_amdgcn_mfma_f32_32x32x16_bf16(ah1, btk_l1, s, 0, 0, 0);
        s = __builtin_amdgcn_mfma_f32_32x32x16_bf16(al1, btk_h1, s, 0, 0, 0);
        __builtin_amdgcn_s_setprio(0);

        // online softmax over q (lane holds one t-column, 16 q rows; partner lane has other 16)
        float pmax = s[0];
#pragma unroll
        for (int r = 1; r < 16; ++r) pmax = fmaxf(pmax, s[r]);
        pmax = fmaxf(pmax, __shfl_xor(pmax, 32));
        if (!__all(pmax <= m + 11.5417f)) {   // defer-max, THR = 8 nats in log2
            float mnew = fmaxf(m, pmax);
            float sc = __builtin_amdgcn_exp2f(m - mnew);
            m = mnew; lsum *= sc;
            acc0 *= sc; acc1 *= sc; acc2 *= sc; acc3 *= sc;
        }
        float pv[16]; float ps = 0.f;
#pragma unroll
        for (int r = 0; r < 16; ++r) { pv[r] = __builtin_amdgcn_exp2f(s[r] - m); ps += pv[r]; }
        lsum += ps;   // lane-partial; merged with partner at epilogue

        // P -> B-operand frags (in-register: cvt_pk + permlane32_swap)
        unsigned a0, a1, a2, a3, c0, c1, c2, c3;
        asm("v_cvt_pk_bf16_f32 %0, %1, %2" : "=v"(a0) : "v"(pv[0]),  "v"(pv[1]));
        asm("v_cvt_pk_bf16_f32 %0, %1, %2" : "=v"(a1) : "v"(pv[2]),  "v"(pv[3]));
        asm("v_cvt_pk_bf16_f32 %0, %1, %2" : "=v"(a2) : "v"(pv[4]),  "v"(pv[5]));
        asm("v_cvt_pk_bf16_f32 %0, %1, %2" : "=v"(a3) : "v"(pv[6]),  "v"(pv[7]));
        asm("v_cvt_pk_bf16_f32 %0, %1, %2" : "=v"(c0) : "v"(pv[8]),  "v"(pv[9]));
        asm("v_cvt_pk_bf16_f32 %0, %1, %2" : "=v"(c1) : "v"(pv[10]), "v"(pv[11]));
        asm("v_cvt_pk_bf16_f32 %0, %1, %2" : "=v"(c2) : "v"(pv[12]), "v"(pv[13]));
        asm("v_cvt_pk_bf16_f32 %0, %1, %2" : "=v"(c3) : "v"(pv[14]), "v"(pv[15]));
        asm("v_permlane32_swap_b32 %0, %1" : "+v"(a0), "+v"(a2));
        asm("v_permlane32_swap_b32 %0, %1" : "+v"(a1), "+v"(a3));
        asm("v_permlane32_swap_b32 %0, %1" : "+v"(c0), "+v"(c2));
        asm("v_permlane32_swap_b32 %0, %1" : "+v"(c1), "+v"(c3));
        union { unsigned u[4]; bf16x8 v; } f0, f1;
        f0.u[0] = a0; f0.u[1] = a1; f0.u[2] = a2; f0.u[3] = a3;
        f1.u[0] = c0; f1.u[1] = c1; f1.u[2] = c2; f1.u[3] = c3;

        // PV: this wave's v-half, A-operands straight from prefetch registers
        __builtin_amdgcn_s_setprio(1);
#pragma unroll
        for (int vs = 0; vs < 4; ++vs) {
            f32x16& a = (vs == 0) ? acc0 : (vs == 1) ? acc1 : (vs == 2) ? acc2 : acc3;
            a = __builtin_amdgcn_mfma_f32_32x32x16_bf16(va[vs][0], f0.v, a, 0, 0, 0);
            a = __builtin_amdgcn_mfma_f32_32x32x16_bf16(va[vs][1], f1.v, a, 0, 0, 0);
        }
        __builtin_amdgcn_s_setprio(0);
    }

    float lt = lsum + __shfl_xor(lsum, 32);
    float linv = 1.f / lt;
    const int tg = t0 + tw * 32 + l31;
    const size_t slab = (size_t)((qg * 20 + n) * 2 + b);
    unsigned short* outp = part2 + slab * 262144;
#pragma unroll
    for (int vs = 0; vs < 4; ++vs) {
        const f32x16& a = (vs == 0) ? acc0 : (vs == 1) ? acc1 : (vs == 2) ? acc2 : acc3;
#pragma unroll
        for (int r = 0; r < 16; ++r) {
            int v = vw * 128 + vs * 32 + (r & 3) + 8 * (r >> 2) + 4 * lh;
            outp[(size_t)v * 1024 + tg] = f2bf(a[r] * linv);
        }
    }
    if (vw == 0 && lh == 0)   // waves 0/1, lanes 0..31: one writer per t-column
        ml_out[slab * 1024 + tg] = make_float2(m, lt);
}

// ---------------- merge 2 q-groups x 20 n-slabs -> bf16 fsm slice ----------------
__global__ __launch_bounds__(256) void reduce40_merge(
    const unsigned short* __restrict__ part,  // [2][20][2][256][1024]
    const float2* __restrict__ ml,            // [2][20][2][1024]
    unsigned short* __restrict__ out)         // [2][256][1024]
{
    size_t i = (size_t)blockIdx.x * 256 + threadIdx.x;   // 0..524287
    const int t = (int)(i & 1023);
    const int b = (int)(i >> 18);
    const int vt_off = (int)(i & 262143);                 // v*1024 + t
    float s = 0.f;
#pragma unroll
    for (int n = 0; n < 20; ++n) {
        float2 ml0 = ml[(size_t)((0 * 20 + n) * 2 + b) * 1024 + t];
        float2 ml1 = ml[(size_t)((20 + n) * 2 + b) * 1024 + t];
        float M = fmaxf(ml0.x, ml1.x);
        float w0 = ml0.y * __builtin_amdgcn_exp2f(ml0.x - M);
        float w1 = ml1.y * __builtin_amdgcn_exp2f(ml1.x - M);
        float inv = 1.f / (w0 + w1);
        float v0 = bf2f(part[(size_t)((0 * 20 + n) * 2 + b) * 262144 + vt_off]);
        float v1 = bf2f(part[(size_t)((20 + n) * 2 + b) * 262144 + vt_off]);
        s += (v0 * w0 + v1 * w1) * inv;
    }
    out[i] = f2bf(s);
}

// ---------------- bilinear upsample 32x32 -> HxH, bf16 in / fp32 out ----------------
__global__ __launch_bounds__(256) void upsample_bf(
    const unsigned short* __restrict__ in,   // level slice [2][256][1024] bf16
    float* __restrict__ out,                 // [2][256][H][H] fp32
    int oh, int ow, int total)
{
    int idx = blockIdx.x * 256 + threadIdx.x;
    if (idx >= total) return;
    int x  = idx % ow;
    int y  = (idx / ow) % oh;
    int bc = idx / (ow * oh);
    float fy = (float)y * 31.0f / (float)(oh - 1);
    float fx = (float)x * 31.0f / (float)(ow - 1);
    int y0 = (int)fy; int y1 = min(y0 + 1, 31); float wy = fy - (float)y0;
    int x0 = (int)fx; int x1 = min(x0 + 1, 31); float wx = fx - (float)x0;
    const unsigned short* p = in + (size_t)bc * 1024;
    float a = bf2f(p[y0 * 32 + x0]), b = bf2f(p[y1 * 32 + x0]);
    float c = bf2f(p[y0 * 32 + x1]), d = bf2f(p[y1 * 32 + x1]);
    float c0 = a + (b - a) * wy;
    float c1 = c + (d - c) * wy;
    out[idx] = c0 + (c1 - c0) * wx;
}

// ---------------- BN stats over (b, spatial) per channel ----------------
__global__ __launch_bounds__(256) void bnstats_kernel(
    const float* __restrict__ fin, float* __restrict__ mu, float* __restrict__ var, int HW)
{
    const int c = blockIdx.x;
    float s = 0.f, s2 = 0.f;
    for (int b = 0; b < 2; ++b) {
        const float* p = fin + ((size_t)b * 256 + c) * HW;
        for (int i = threadIdx.x; i < HW; i += 256) {
            float v = p[i]; s += v; s2 += v * v;
        }
    }
#pragma unroll
    for (int off = 32; off; off >>= 1) {
        s  += __shfl_xor(s, off);
        s2 += __shfl_xor(s2, off);
    }
    __shared__ float r1[4], r2[4];
    if ((threadIdx.x & 63) == 0) { r1[threadIdx.x >> 6] = s; r2[threadIdx.x >> 6] = s2; }
    __syncthreads();
    if (threadIdx.x == 0) {
        float cnt = 2.f * (float)HW;
        float mm = (r1[0] + r1[1] + r1[2] + r1[3]) / cnt;
        float qq = (r2[0] + r2[1] + r2[2] + r2[3]) / cnt;
        mu[c] = mm; var[c] = qq - mm * mm;
    }
}

// ---------------- fold BN into comb weights ----------------
__global__ __launch_bounds__(256) void prep_comb(
    const float* __restrict__ comb_w, const float* __restrict__ comb_b,
    const float* __restrict__ gamma, const float* __restrict__ beta,
    const float* __restrict__ mu, const float* __restrict__ var,
    short* __restrict__ wc, float* __restrict__ bias2)
{
    const int oc = blockIdx.x;
    const int ic = threadIdx.x;
    float a  = gamma[ic] * rsqrtf(var[ic] + 1e-5f);
    float bb = beta[ic] - mu[ic] * a;
    float w1 = comb_w[(size_t)oc * 512 + ic];
    float w2 = comb_w[(size_t)oc * 512 + 256 + ic];
    wc[(size_t)oc * 512 + ic]       = (short)f2bf(w1);
    wc[(size_t)oc * 512 + 256 + ic] = (short)f2bf(w2 * a);
    float s = w2 * bb;
#pragma unroll
    for (int off = 32; off; off >>= 1) s += __shfl_xor(s, off);
    __shared__ float red[4];
    if ((threadIdx.x & 63) == 0) red[threadIdx.x >> 6] = s;
    __syncthreads();
    if (threadIdx.x == 0)
        bias2[oc] = comb_b[oc] + red[0] + red[1] + red[2] + red[3];
}

// ---------------- comb 1x1 conv as MFMA GEMM (fp32 fin) ----------------
__global__ __launch_bounds__(256, 1) void comb_mfma(
    const float* __restrict__ f,    // [2][256][HW]
    const float* __restrict__ fin,  // [2][256][HW] fp32
    const short* __restrict__ wc,   // [256][512] bf16
    const float* __restrict__ bias2,
    float* __restrict__ out, int HW)
{
    __shared__ short s_wc[256 * 40];
    __shared__ short s_xc[128 * 40];
    const int tid = threadIdx.x;
    const int p0 = blockIdx.x * 128;
    const int b  = blockIdx.y;
    const int wv = tid >> 6, l31 = tid & 31, lh = (tid >> 5) & 1;
    const int wm = wv >> 1, wn = wv & 1;

    f32x16 acc[4][2];
#pragma unroll
    for (int i = 0; i < 4; ++i)
#pragma unroll
        for (int j = 0; j < 2; ++j)
#pragma unroll
            for (int r = 0; r < 16; ++r) acc[i][j][r] = 0.f;

    for (int k0 = 0; k0 < 512; k0 += 32) {
        __syncthreads();
        for (int u = tid; u < 512; u += 256) {
            int r = u >> 1, h = u & 1;
            *(bf16x8*)&s_wc[r * 40 + h * 16 + 0] = *(const bf16x8*)&wc[(size_t)r * 512 + k0 + h * 16];
            *(bf16x8*)&s_wc[r * 40 + h * 16 + 8] = *(const bf16x8*)&wc[(size_t)r * 512 + k0 + h * 16 + 8];
        }
        for (int u = tid; u < 1024; u += 256) {
            int kr = u >> 5, n4 = (u & 31) * 4;
            int ck = k0 + kr;
            const float* bsrc = (ck < 256)
                ? f   + ((size_t)(b * 256 + ck)) * HW
                : fin + ((size_t)(b * 256 + ck - 256)) * HW;
            int p = p0 + n4;
            float v0, v1, v2, v3;
            if (p + 3 < HW) {
                float4 v4 = *(const float4*)&bsrc[p];
                v0 = v4.x; v1 = v4.y; v2 = v4.z; v3 = v4.w;
            } else {
                v0 = bsrc[min(p,     HW - 1)];
                v1 = bsrc[min(p + 1, HW - 1)];
                v2 = bsrc[min(p + 2, HW - 1)];
                v3 = bsrc[min(p + 3, HW - 1)];
            }
            s_xc[(n4 + 0) * 40 + kr] = (short)f2bf(v0);
            s_xc[(n4 + 1) * 40 + kr] = (short)f2bf(v1);
            s_xc[(n4 + 2) * 40 + kr] = (short)f2bf(v2);
            s_xc[(n4 + 3) * 40 + kr] = (short)f2bf(v3);
        }
        __syncthreads();
#pragma unroll
        for (int ks = 0; ks < 2; ++ks) {
            bf16x8 a[4], bx[2];
#pragma unroll
            for (int mi = 0; mi < 4; ++mi)
                a[mi] = *(const bf16x8*)&s_wc[(wm * 128 + mi * 32 + l31) * 40 + ks * 16 + lh * 8];
#pragma unroll
            for (int ni = 0; ni < 2; ++ni)
                bx[ni] = *(const bf16x8*)&s_xc[(wn * 64 + ni * 32 + l31) * 40 + ks * 16 + lh * 8];
#pragma unroll
            for (int mi = 0; mi < 4; ++mi)
#pragma unroll
                for (int ni = 0; ni < 2; ++ni)
                    acc[mi][ni] = __builtin_amdgcn_mfma_f32_32x32x16_bf16(a[mi], bx[ni], acc[mi][ni], 0, 0, 0);
        }
    }
#pragma unroll
    for (int mi = 0; mi < 4; ++mi) {
#pragma unroll
        for (int ni = 0; ni < 2; ++ni) {
            int p = p0 + wn * 64 + ni * 32 + l31;
            if (p < HW) {
#pragma unroll
                for (int r = 0; r < 16; ++r) {
                    int oc = wm * 128 + mi * 32 + (r & 3) + 8 * (r >> 2) + 4 * lh;
                    out[((size_t)(b * 256 + oc)) * HW + p] = acc[mi][ni][r] + bias2[oc];
                }
            }
        }
    }
}

// ---------------- host orchestration ----------------
extern "C" void kernel_launch(void* const* d_in, const int* in_sizes, int n_in,
                              void* d_out, int out_size, void* d_ws, size_t ws_size,
                              hipStream_t stream) {
    if (ws_size < WS_BYTES) return;

    const float* feats[5];
    for (int i = 0; i < 5; ++i) feats[i] = (const float*)d_in[i];
    const float* attn     = (const float*)d_in[5];
    const float* key_t_w  = (const float*)d_in[6];
    const float* key_t_b  = (const float*)d_in[7];
    const float* val_t_w  = (const float*)d_in[8];
    const float* val_t_b  = (const float*)d_in[9];
    const float* key_q_w  = (const float*)d_in[10];
    const float* key_q_b  = (const float*)d_in[11];
    const float* val_q_w  = (const float*)d_in[12];
    const float* val_q_b  = (const float*)d_in[13];
    const float* bn_gamma = (const float*)d_in[14];
    const float* bn_beta  = (const float*)d_in[15];
    const float* comb_w   = (const float*)d_in[16];
    const float* comb_b   = (const float*)d_in[17];

    char* ws = (char*)d_ws;
    float* biasc = (float*)(ws + B_BIASC);
    unsigned short* kt_hi = (unsigned short*)(ws + B_KTH);
    unsigned short* kt_lo = (unsigned short*)(ws + B_KTL);
    unsigned short* vt    = (unsigned short*)(ws + B_VT);
    unsigned short* kq_hi = (unsigned short*)(ws + B_KQH);
    unsigned short* kq_lo = (unsigned short*)(ws + B_KQL);
    unsigned short* vq    = (unsigned short*)(ws + B_VQ);
    float* mean_f = (float*)(ws + B_MEAN);
    unsigned short* fsm = (unsigned short*)(ws + B_FSM);
    float* mu     = (float*)(ws + B_MU);
    float* var    = (float*)(ws + B_VAR);
    short* wc_bf  = (short*)(ws + B_WC);
    float* bias2  = (float*)(ws + B_BIAS2);
    unsigned short* X_h = (unsigned short*)(ws + B_UNION + U_XH);
    unsigned short* X_l = (unsigned short*)(ws + B_UNION + U_XL);
    short* wp_hi = (short*)(ws + B_UNION + U_WPH);
    short* wp_lo = (short*)(ws + B_UNION + U_WPL);
    unsigned short* part2 = (unsigned short*)(ws + B_UNION + U_FPART);
    float2* ml_arr = (float2*)(ws + B_ML);
    float* fin_big = (float*)(ws + B_UNION);   // overwrites part2 after reduce40

    prep_weights<<<dim3(160, 6), 256, 0, stream>>>(
        key_t_w, key_t_b, val_t_w, val_t_b, key_q_w, key_q_b, val_q_w, val_q_b,
        wp_hi, wp_lo, biasc);

    transpose_split<<<dim3(20, 16, 4), 256, 0, stream>>>(attn, X_h, X_l);

    mean2d_all<<<dim3(512, 5), 256, 0, stream>>>(
        feats[0], feats[1], feats[2], feats[3], feats[4], mean_f);

    resizeT_all<<<dim3(2, 16, 20), 256, 0, stream>>>(
        feats[0], feats[1], feats[2], feats[3], feats[4], mean_f, X_h, X_l);

    conv3x3_all<<<dim3(5, 16, 30), 256, 0, stream>>>(
        X_h, X_l, wp_hi, wp_lo, biasc, kt_hi, kt_lo, vt, kq_hi, kq_lo, vq);

    size_t out_off = 0;
    for (int idx = 0; idx < 5; ++idx) {
        const int H = 128 >> idx, HW = H * H;
        const int total = 2 * 256 * HW;

        flash5<<<dim3(16, 2, 40), 256, 0, stream>>>(
            kt_hi, kt_lo, vt,
            kq_hi + (size_t)idx * 2 * 32768,
            kq_lo + (size_t)idx * 2 * 32768,
            vq + (size_t)idx * 2 * 131072,
            part2, ml_arr);

        reduce40_merge<<<2048, 256, 0, stream>>>(part2, ml_arr, fsm + (size_t)idx * 524288);

        upsample_bf<<<(total + 255) / 256, 256, 0, stream>>>(
            fsm + (size_t)idx * 524288, fin_big, H, H, total);

        bnstats_kernel<<<256, 256, 0, stream>>>(fin_big, mu + idx * 256, var + idx * 256, HW);

        prep_comb<<<256, 256, 0, stream>>>(
            comb_w, comb_b, bn_gamma + idx * 256, bn_beta + idx * 256,
            mu + idx * 256, var + idx * 256, wc_bf + (size_t)idx * 131072, bias2 + idx * 256);

        comb_mfma<<<dim3((HW + 127) / 128, 2), 256, 0, stream>>>(
            feats[idx], fin_big, wc_bf + (size_t)idx * 131072, bias2 + idx * 256,
            (float*)d_out + out_off, HW);

        out_off += (size_t)2 * 256 * HW;
    }
}

// Round 12
// 871.147 us; speedup vs baseline: 1.2431x; 1.2149x over previous
//
#include <hip/hip_runtime.h>
#include <cstddef>
#include <cstdint>

typedef __attribute__((ext_vector_type(8))) short bf16x8;
typedef __attribute__((ext_vector_type(16))) float f32x16;
typedef __attribute__((ext_vector_type(4))) unsigned short us4;

// ---------------- workspace layout (byte offsets) ----------------
static const size_t B_BIASC = 0;            // 6*160*4 = 3,840
static const size_t B_KTH   = 3840;         // 20*1024*32*2 = 1,310,720
static const size_t B_KTL   = 1314560;      // 1,310,720
static const size_t B_VT    = 2625280;      // 20*128*1024*2 = 5,242,880
static const size_t B_KQH   = 7868160;      // 5*2*1024*32*2 = 655,360
static const size_t B_KQL   = 8523520;      // 655,360
static const size_t B_VQ    = 9178880;      // 5*2*128*1024*2 = 2,621,440
static const size_t B_MEAN  = 11800320;     // 5*512*4 = 10,240
static const size_t B_FSM   = 11810560;     // 5*2*256*1024*2 = 5,242,880 (bf16)
static const size_t B_MU    = 17053440;     // 5*256*4 = 5,120
static const size_t B_VAR   = 17058560;     // 5,120
static const size_t B_WC    = 17063680;     // 5*256*512*2 = 1,310,720
static const size_t B_BIAS2 = 18374400;     // 5,120
static const size_t B_UNION = 18379520;     // 41,943,040 union region
// phase 1: X_all_hi +0 (15,728,640), X_all_lo +15,728,640, wp_hi +31,457,280, wp_lo +35,880,960
// phase 2 (per level): part2 +0 (2*20*2*256*1024*2 = 41,943,040) -> reduce40 -> fsm
static const size_t U_XH    = 0;
static const size_t U_XL    = 15728640;
static const size_t U_WPH   = 31457280;
static const size_t U_WPL   = 35880960;
static const size_t U_FPART = 0;
static const size_t B_ML    = 60322560;     // 2*20*2*1024*8 = 655,360 (float2 m,l)
static const size_t WS_BYTES = 60977920;    // ~61.0 MB

// ---------------- bf16 helpers (RNE) ----------------
__device__ inline unsigned short f2bf(float x) {
    unsigned u = __float_as_uint(x);
    return (unsigned short)((u + 0x7fffu + ((u >> 16) & 1u)) >> 16);
}
__device__ inline float bf2f(unsigned short u) {
    return __uint_as_float(((unsigned)u) << 16);
}
__device__ inline void bf16split(float x, unsigned short& hi, unsigned short& lo) {
    unsigned u = __float_as_uint(x);
    unsigned hb = (u + 0x7fffu + ((u >> 16) & 1u)) >> 16;
    hi = (unsigned short)hb;
    float hf = __uint_as_float(hb << 16);
    float r = x - hf;
    unsigned ur = __float_as_uint(r);
    lo = (unsigned short)((ur + 0x7fffu + ((ur >> 16) & 1u)) >> 16);
}
__device__ inline const float* sel5(const float* a, const float* b, const float* c,
                                    const float* d, const float* e, int i) {
    return i == 0 ? a : i == 1 ? b : i == 2 ? c : i == 3 ? d : e;
}

// ---------------- weight pre-transform ----------------
__global__ __launch_bounds__(256) void prep_weights(
    const float* __restrict__ kt_w, const float* __restrict__ kt_b,
    const float* __restrict__ vt_w, const float* __restrict__ vt_b,
    const float* __restrict__ kq_w, const float* __restrict__ kq_b,
    const float* __restrict__ vq_w, const float* __restrict__ vq_b,
    short* __restrict__ wp_hi, short* __restrict__ wp_lo, float* __restrict__ biasc)
{
    const int oc = blockIdx.x;    // 0..159
    const int s  = blockIdx.y;    // 0..5 (0 = stage A, 1+idx = level)
    const int ic = threadIdx.x;   // 0..255
    const bool iskey = oc < 32;
    const int ocl = iskey ? oc : oc - 32;
    const float scale = (iskey && s > 0) ? 1.4426950408889634f : 1.0f;
    const float* w = iskey
        ? (s == 0 ? kt_w : kq_w + (size_t)(s - 1) * 32 * 256 * 9)
        : (s == 0 ? vt_w : vq_w + (size_t)(s - 1) * 128 * 256 * 9);
    const float* wsrc = w + ((size_t)ocl * 256 + ic) * 9;
#pragma unroll
    for (int t = 0; t < 9; ++t) {
        unsigned short h, l; bf16split(wsrc[t] * scale, h, l);
        size_t d = ((size_t)(s * 9 + t) * 160 + oc) * 256 + ic;
        wp_hi[d] = (short)h; wp_lo[d] = (short)l;
    }
    if (ic == 0) {
        const float* bptr = iskey
            ? (s == 0 ? kt_b : kq_b + (s - 1) * 32)
            : (s == 0 ? vt_b : vq_b + (s - 1) * 128);
        biasc[s * 160 + oc] = bptr[ocl] * scale;
    }
}

// ---------------- fp32 [20][256][1024] -> bf16 hi/lo X_all imgs 0..19 ----------------
__global__ __launch_bounds__(256) void transpose_split(
    const float* __restrict__ in,
    unsigned short* __restrict__ oh, unsigned short* __restrict__ ol)
{
    __shared__ float s[16][260];
    const int n = blockIdx.x, ch = blockIdx.y, p0 = blockIdx.z * 256;
    const int tid = threadIdx.x;
#pragma unroll
    for (int i = 0; i < 16; ++i)
        s[i][tid] = in[((size_t)(n * 256 + ch * 16 + i)) * 1024 + p0 + tid];
    __syncthreads();
    union { unsigned short u[16]; bf16x8 v[2]; } h8, l8;
#pragma unroll
    for (int i = 0; i < 16; ++i) bf16split(s[i][tid], h8.u[i], l8.u[i]);
    size_t base = ((size_t)(n * 16 + ch) * 1024 + p0 + tid) * 16;
    *(bf16x8*)&oh[base] = h8.v[0]; *(bf16x8*)&oh[base + 8] = h8.v[1];
    *(bf16x8*)&ol[base] = l8.v[0]; *(bf16x8*)&ol[base + 8] = l8.v[1];
}

// ---------------- batched per (lvl,b,c) spatial mean ----------------
__global__ __launch_bounds__(256) void mean2d_all(
    const float* f0, const float* f1, const float* f2, const float* f3, const float* f4,
    float* __restrict__ mean)
{
    const int lvl = blockIdx.y;
    const float* f = sel5(f0, f1, f2, f3, f4, lvl);
    const int H = 128 >> lvl, HW = H * H;
    const int bc = blockIdx.x;
    const float* src = f + (size_t)bc * HW;
    float s = 0.f;
    for (int i = threadIdx.x; i < HW; i += 256) s += src[i];
#pragma unroll
    for (int off = 32; off; off >>= 1) s += __shfl_xor(s, off);
    __shared__ float red[4];
    if ((threadIdx.x & 63) == 0) red[threadIdx.x >> 6] = s;
    __syncthreads();
    if (threadIdx.x == 0)
        mean[lvl * 512 + bc] = (red[0] + red[1] + red[2] + red[3]) / (float)HW;
}

// ---------------- batched resize (HxH->32x32) + mean-sub -> X_all imgs 20..29 ----------------
__global__ __launch_bounds__(256) void resizeT_all(
    const float* f0, const float* f1, const float* f2, const float* f3, const float* f4,
    const float* __restrict__ mean,
    unsigned short* __restrict__ oh, unsigned short* __restrict__ ol)
{
    __shared__ float s[16][260];
    const int lvl = blockIdx.z >> 2;
    const int p0 = (blockIdx.z & 3) * 256;
    const int b = blockIdx.x, ch = blockIdx.y;
    const float* f = sel5(f0, f1, f2, f3, f4, lvl);
    const int H = 128 >> lvl;
    const int img = 20 + lvl * 2 + b;
    const int tid = threadIdx.x;
    const int p = p0 + tid, y = p >> 5, x = p & 31;
    float fy = (float)y * (float)(H - 1) / 31.0f;
    float fx = (float)x * (float)(H - 1) / 31.0f;
    int y0 = (int)fy; int y1 = min(y0 + 1, H - 1); float wy = fy - (float)y0;
    int x0 = (int)fx; int x1 = min(x0 + 1, H - 1); float wx = fx - (float)x0;
#pragma unroll
    for (int i = 0; i < 16; ++i) {
        int c = ch * 16 + i;
        const float* pf = f + ((size_t)(b * 256 + c)) * H * H;
        float a = pf[y0 * H + x0], bb = pf[y1 * H + x0];
        float cc = pf[y0 * H + x1], d = pf[y1 * H + x1];
        float c0 = a + (bb - a) * wy;
        float c1 = cc + (d - cc) * wy;
        s[i][tid] = c0 + (c1 - c0) * wx - mean[lvl * 512 + b * 256 + c];
    }
    __syncthreads();
    union { unsigned short u[16]; bf16x8 v[2]; } h8, l8;
#pragma unroll
    for (int i = 0; i < 16; ++i) bf16split(s[i][tid], h8.u[i], l8.u[i]);
    size_t base = ((size_t)(img * 16 + ch) * 1024 + p) * 16;
    *(bf16x8*)&oh[base] = h8.v[0]; *(bf16x8*)&oh[base + 8] = h8.v[1];
    *(bf16x8*)&ol[base] = l8.v[0]; *(bf16x8*)&ol[base + 8] = l8.v[1];
}

// ---------------- merged direct MFMA 3x3 conv, XCD-swizzled 1D grid ----------------
// grid 2560 x 256. bid -> xcd=bid&7, grp=(bid>>3)%5, yp=((bid>>3)/5)&15, imgh=((bid>>3)/5)>>4,
// img = xcd + 8*imgh. All 80 blocks of one image share an XCD's L2.
__global__ __launch_bounds__(256) void conv3x3_all(
    const unsigned short* __restrict__ xT_h,  // [30][16][1024][16]
    const unsigned short* __restrict__ xT_l,
    const short* __restrict__ wp_hi_all,      // [6][9][160][256]
    const short* __restrict__ wp_lo_all,
    const float* __restrict__ biasc_all,      // [6][160]
    unsigned short* __restrict__ kt_hi, unsigned short* __restrict__ kt_lo, // [20][1024][32]
    unsigned short* __restrict__ vt,                                         // [20][128][1024]
    unsigned short* __restrict__ kq_hi, unsigned short* __restrict__ kq_lo, // [10][1024][32]
    unsigned short* __restrict__ vq)                                         // [10][128][1024]
{
    const int bid = blockIdx.x;
    const int xcd = bid & 7;
    const int j   = bid >> 3;        // 0..319
    const int grp = j % 5;
    const int k   = j / 5;           // 0..63
    const int yp  = k & 15;
    const int imgh = k >> 4;         // 0..3
    const int img = xcd + 8 * imgh;  // 0..31
    if (img >= 30) return;

    __shared__ float s_red[4][2][16][64];     // 32 KB
    const int tid = threadIdx.x;
    const bool iskey = (grp == 0);
    const int set = (img < 20) ? 0 : 1 + ((img - 20) >> 1);
    const int ocb = grp * 32;
    const int wave = tid >> 6, lane = tid & 63, l31 = tid & 31, lh = (tid >> 5) & 1;
    const int y0 = yp * 2;

    f32x16 acc0 = {}, acc1 = {};
    const bf16x8 bz = {};
    const unsigned short* xh = xT_h + (size_t)img * 16 * 16384;
    const unsigned short* xl = xT_l + (size_t)img * 16 * 16384;
    const short* wph = wp_hi_all + (size_t)set * 368640;
    const short* wpl = wp_lo_all + (size_t)set * 368640;
    const float* bset = biasc_all + set * 160;

    for (int cc = 0; cc < 4; ++cc) {
        const int ch = (wave << 2) + cc;
        const unsigned short* xhc = xh + (size_t)ch * 16384 + lh * 8;
        const unsigned short* xlc = xl + (size_t)ch * 16384 + lh * 8;
#pragma unroll
        for (int tg = 0; tg < 3; ++tg) {
            bf16x8 wh[3], wl[3];
#pragma unroll
            for (int tl = 0; tl < 3; ++tl) {
                size_t wi = ((size_t)((tg * 3 + tl) * 160 + ocb + l31)) * 256 + (ch << 4) + lh * 8;
                wh[tl] = *(const bf16x8*)&wph[wi];
                if (iskey) wl[tl] = *(const bf16x8*)&wpl[wi];
            }
#pragma unroll
            for (int nt = 0; nt < 2; ++nt) {
                const int ri = y0 + nt - 1 + tg;
                const bool rok = (ri >= 0 && ri < 32);
#pragma unroll
                for (int tl = 0; tl < 3; ++tl) {
                    const int x = l31 + tl - 1;
                    const bool ok = rok && (x >= 0) && (x < 32);
                    bf16x8 bh = bz, bl = bz;
                    if (ok) {
                        const int p = ri * 32 + x;
                        bh = *(const bf16x8*)&xhc[p * 16];
                        if (iskey) bl = *(const bf16x8*)&xlc[p * 16];
                    }
                    f32x16& a = nt ? acc1 : acc0;
                    a = __builtin_amdgcn_mfma_f32_32x32x16_bf16(wh[tl], bh, a, 0, 0, 0);
                    if (iskey) {
                        a = __builtin_amdgcn_mfma_f32_32x32x16_bf16(wh[tl], bl, a, 0, 0, 0);
                        a = __builtin_amdgcn_mfma_f32_32x32x16_bf16(wl[tl], bh, a, 0, 0, 0);
                    }
                }
            }
        }
    }
    // cross-wave ic reduce through LDS
#pragma unroll
    for (int r = 0; r < 16; ++r) {
        s_red[wave][0][r][lane] = acc0[r];
        s_red[wave][1][r][lane] = acc1[r];
    }
    __syncthreads();
    float r0[4], r1[4];
#pragma unroll
    for (int jj = 0; jj < 4; ++jj) {
        int r = (wave << 2) + jj;
        r0[jj] = s_red[0][0][r][lane] + s_red[1][0][r][lane] + s_red[2][0][r][lane] + s_red[3][0][r][lane];
        r1[jj] = s_red[0][1][r][lane] + s_red[1][1][r][lane] + s_red[2][1][r][lane] + s_red[3][1][r][lane];
    }
    // epilogue: wave w owns the r-quad qd = w
    if (iskey) {
#pragma unroll
        for (int nt = 0; nt < 2; ++nt) {
            const float* rr = nt ? r1 : r0;
            int p = (y0 + nt) * 32 + l31;
            int ocq = 8 * wave + 4 * lh;
            us4 h4, l4;
#pragma unroll
            for (int jj = 0; jj < 4; ++jj) {
                unsigned short h, l;
                bf16split(rr[jj] + bset[ocq + jj], h, l);
                h4[jj] = h; l4[jj] = l;
            }
            if (img < 20) {
                size_t base = ((size_t)img * 1024 + p) * 32;
                *(us4*)&kt_hi[base + ocq] = h4;
                *(us4*)&kt_lo[base + ocq] = l4;
            } else {
                size_t base = ((size_t)(img - 20) * 1024 + p) * 32;
                *(us4*)&kq_hi[base + ocq] = h4;
                *(us4*)&kq_lo[base + ocq] = l4;
            }
        }
    } else {
#pragma unroll
        for (int nt = 0; nt < 2; ++nt) {
            const float* rr = nt ? r1 : r0;
            int p = (y0 + nt) * 32 + l31;
#pragma unroll
            for (int jj = 0; jj < 4; ++jj) {
                int pat = jj + 8 * wave + 4 * lh;
                int vo = (ocb - 32) + pat;
                unsigned short val = f2bf(rr[jj] + bset[32 + vo]);
                if (img < 20) vt[((size_t)img * 128 + vo) * 1024 + p] = val;
                else          vq[((size_t)(img - 20) * 128 + vo) * 1024 + p] = val;
            }
        }
    }
}

// ---------------- flash relation-attention v5 (unchanged from round 11) ----------------
__global__ __launch_bounds__(256, 2) void flash5(
    const unsigned short* __restrict__ kt_hi, const unsigned short* __restrict__ kt_lo,
    const unsigned short* __restrict__ vt_bf,
    const unsigned short* __restrict__ kq_hi, const unsigned short* __restrict__ kq_lo,
    const unsigned short* __restrict__ vq_bf,
    unsigned short* __restrict__ part2,      // [2 qg][20 n][2 b][256][1024] bf16
    float2* __restrict__ ml_out)             // [2 qg][20 n][2 b][1024] (m, l)
{
    const int tid = threadIdx.x;
    const int t0 = blockIdx.x * 64;
    const int b  = blockIdx.y;
    const int n  = blockIdx.z >> 1;
    const int qg = blockIdx.z & 1;
    const int qbase = qg * 512;
    const int wave = tid >> 6, lane = tid & 63, l31 = lane & 31, lh = lane >> 5;
    const int tw = wave & 1, vw = wave >> 1;

    const int trow = t0 + tw * 32 + l31;
    bf16x8 btk_h0, btk_h1, btk_l0, btk_l1;
    {
        size_t g = ((size_t)n * 1024 + trow) * 32 + lh * 8;
        btk_h0 = *(const bf16x8*)&kt_hi[g];
        btk_h1 = *(const bf16x8*)&kt_hi[g + 16];
        btk_l0 = *(const bf16x8*)&kt_lo[g];
        btk_l1 = *(const bf16x8*)&kt_lo[g + 16];
    }

    const unsigned short* vbase = (vw == 0)
        ? (vq_bf + (size_t)b * 131072)
        : (vt_bf + (size_t)n * 131072);
    const unsigned short* vrow[4];
#pragma unroll
    for (int vs = 0; vs < 4; ++vs)
        vrow[vs] = vbase + ((size_t)(vs * 32 + l31)) * 1024 + lh * 8;

    const unsigned short* kqh = kq_hi + (size_t)b * 1024 * 32;
    const unsigned short* kql = kq_lo + (size_t)b * 1024 * 32;

    bf16x8 nva[4][2];
#pragma unroll
    for (int vs = 0; vs < 4; ++vs) {
        nva[vs][0] = *(const bf16x8*)&vrow[vs][qbase];
        nva[vs][1] = *(const bf16x8*)&vrow[vs][qbase + 16];
    }
    bf16x8 nah0 = *(const bf16x8*)&kqh[(size_t)(qbase + l31) * 32 + lh * 8];
    bf16x8 nah1 = *(const bf16x8*)&kqh[(size_t)(qbase + l31) * 32 + 16 + lh * 8];
    bf16x8 nal0 = *(const bf16x8*)&kql[(size_t)(qbase + l31) * 32 + lh * 8];
    bf16x8 nal1 = *(const bf16x8*)&kql[(size_t)(qbase + l31) * 32 + 16 + lh * 8];

    f32x16 acc0 = {}, acc1 = {}, acc2 = {}, acc3 = {};
    float m = -3.0e38f, lsum = 0.f;

    for (int q0 = qbase; q0 < qbase + 512; q0 += 32) {
        bf16x8 va[4][2];
#pragma unroll
        for (int vs = 0; vs < 4; ++vs) { va[vs][0] = nva[vs][0]; va[vs][1] = nva[vs][1]; }
        bf16x8 ah0 = nah0, ah1 = nah1, al0 = nal0, al1 = nal1;

        if (q0 + 32 < qbase + 512) {
            const int qn = q0 + 32;
#pragma unroll
            for (int vs = 0; vs < 4; ++vs) {
                nva[vs][0] = *(const bf16x8*)&vrow[vs][qn];
                nva[vs][1] = *(const bf16x8*)&vrow[vs][qn + 16];
            }
            size_t kb = (size_t)(qn + l31) * 32 + lh * 8;
            nah0 = *(const bf16x8*)&kqh[kb];
            nah1 = *(const bf16x8*)&kqh[kb + 16];
            nal0 = *(const bf16x8*)&kql[kb];
            nal1 = *(const bf16x8*)&kql[kb + 16];
        }

        f32x16 s = {};
        __builtin_amdgcn_s_setprio(1);
        s = __builtin_amdgcn_mfma_f32_32x32x16_bf16(ah0, btk_h0, s, 0, 0, 0);
        s = __builtin_amdgcn_mfma_f32_32x32x16_bf16(ah0, btk_l0, s, 0, 0, 0);
        s = __builtin_amdgcn_mfma_f32_32x32x16_bf16(al0, btk_h0, s, 0, 0, 0);
        s = __builtin_amdgcn_mfma_f32_32x32x16_bf16(ah1, btk_h1, s, 0, 0, 0);
        s = __builtin_amdgcn_mfma_f32_32x32x16_bf16(ah1, btk_l1, s, 0, 0, 0);
        s = __builtin_amdgcn_mfma_f32_32x32x16_bf16(al1, btk_h1, s, 0, 0, 0);
        __builtin_amdgcn_s_setprio(0);

        float pmax = s[0];
#pragma unroll
        for (int r = 1; r < 16; ++r) pmax = fmaxf(pmax, s[r]);
        pmax = fmaxf(pmax, __shfl_xor(pmax, 32));
        if (!__all(pmax <= m + 11.5417f)) {
            float mnew = fmaxf(m, pmax);
            float sc = __builtin_amdgcn_exp2f(m - mnew);
            m = mnew; lsum *= sc;
            acc0 *= sc; acc1 *= sc; acc2 *= sc; acc3 *= sc;
        }
        float pv[16]; float ps = 0.f;
#pragma unroll
        for (int r = 0; r < 16; ++r) { pv[r] = __builtin_amdgcn_exp2f(s[r] - m); ps += pv[r]; }
        lsum += ps;

        unsigned a0, a1, a2, a3, c0, c1, c2, c3;
        asm("v_cvt_pk_bf16_f32 %0, %1, %2" : "=v"(a0) : "v"(pv[0]),  "v"(pv[1]));
        asm("v_cvt_pk_bf16_f32 %0, %1, %2" : "=v"(a1) : "v"(pv[2]),  "v"(pv[3]));
        asm("v_cvt_pk_bf16_f32 %0, %1, %2" : "=v"(a2) : "v"(pv[4]),  "v"(pv[5]));
        asm("v_cvt_pk_bf16_f32 %0, %1, %2" : "=v"(a3) : "v"(pv[6]),  "v"(pv[7]));
        asm("v_cvt_pk_bf16_f32 %0, %1, %2" : "=v"(c0) : "v"(pv[8]),  "v"(pv[9]));
        asm("v_cvt_pk_bf16_f32 %0, %1, %2" : "=v"(c1) : "v"(pv[10]), "v"(pv[11]));
        asm("v_cvt_pk_bf16_f32 %0, %1, %2" : "=v"(c2) : "v"(pv[12]), "v"(pv[13]));
        asm("v_cvt_pk_bf16_f32 %0, %1, %2" : "=v"(c3) : "v"(pv[14]), "v"(pv[15]));
        asm("v_permlane32_swap_b32 %0, %1" : "+v"(a0), "+v"(a2));
        asm("v_permlane32_swap_b32 %0, %1" : "+v"(a1), "+v"(a3));
        asm("v_permlane32_swap_b32 %0, %1" : "+v"(c0), "+v"(c2));
        asm("v_permlane32_swap_b32 %0, %1" : "+v"(c1), "+v"(c3));
        union { unsigned u[4]; bf16x8 v; } f0, f1;
        f0.u[0] = a0; f0.u[1] = a1; f0.u[2] = a2; f0.u[3] = a3;
        f1.u[0] = c0; f1.u[1] = c1; f1.u[2] = c2; f1.u[3] = c3;

        __builtin_amdgcn_s_setprio(1);
#pragma unroll
        for (int vs = 0; vs < 4; ++vs) {
            f32x16& a = (vs == 0) ? acc0 : (vs == 1) ? acc1 : (vs == 2) ? acc2 : acc3;
            a = __builtin_amdgcn_mfma_f32_32x32x16_bf16(va[vs][0], f0.v, a, 0, 0, 0);
            a = __builtin_amdgcn_mfma_f32_32x32x16_bf16(va[vs][1], f1.v, a, 0, 0, 0);
        }
        __builtin_amdgcn_s_setprio(0);
    }

    float lt = lsum + __shfl_xor(lsum, 32);
    float linv = 1.f / lt;
    const int tg = t0 + tw * 32 + l31;
    const size_t slab = (size_t)((qg * 20 + n) * 2 + b);
    unsigned short* outp = part2 + slab * 262144;
#pragma unroll
    for (int vs = 0; vs < 4; ++vs) {
        const f32x16& a = (vs == 0) ? acc0 : (vs == 1) ? acc1 : (vs == 2) ? acc2 : acc3;
#pragma unroll
        for (int r = 0; r < 16; ++r) {
            int v = vw * 128 + vs * 32 + (r & 3) + 8 * (r >> 2) + 4 * lh;
            outp[(size_t)v * 1024 + tg] = f2bf(a[r] * linv);
        }
    }
    if (vw == 0 && lh == 0)
        ml_out[slab * 1024 + tg] = make_float2(m, lt);
}

// ---------------- merge 2 q-groups x 20 n-slabs -> bf16 fsm slice ----------------
__global__ __launch_bounds__(256) void reduce40_merge(
    const unsigned short* __restrict__ part,  // [2][20][2][256][1024]
    const float2* __restrict__ ml,            // [2][20][2][1024]
    unsigned short* __restrict__ out)         // [2][256][1024]
{
    size_t i = (size_t)blockIdx.x * 256 + threadIdx.x;   // 0..524287
    const int t = (int)(i & 1023);
    const int b = (int)(i >> 18);
    const int vt_off = (int)(i & 262143);                 // v*1024 + t
    float s = 0.f;
#pragma unroll
    for (int n = 0; n < 20; ++n) {
        float2 ml0 = ml[(size_t)((0 * 20 + n) * 2 + b) * 1024 + t];
        float2 ml1 = ml[(size_t)((20 + n) * 2 + b) * 1024 + t];
        float M = fmaxf(ml0.x, ml1.x);
        float w0 = ml0.y * __builtin_amdgcn_exp2f(ml0.x - M);
        float w1 = ml1.y * __builtin_amdgcn_exp2f(ml1.x - M);
        float inv = 1.f / (w0 + w1);
        float v0 = bf2f(part[(size_t)((0 * 20 + n) * 2 + b) * 262144 + vt_off]);
        float v1 = bf2f(part[(size_t)((20 + n) * 2 + b) * 262144 + vt_off]);
        s += (v0 * w0 + v1 * w1) * inv;
    }
    out[i] = f2bf(s);
}

// ---------------- BN stats with fused bilinear upsample (32x32 -> HxH), all levels ----------------
// grid (256 c, 5 lvl)
__global__ __launch_bounds__(256) void bnstats2_all(
    const unsigned short* __restrict__ fsm, float* __restrict__ mu, float* __restrict__ var)
{
    const int c = blockIdx.x, lvl = blockIdx.y;
    const int lg = 7 - lvl, H = 128 >> lvl, HW = H * H;
    const float sc = 31.f / (float)(H - 1);
    float s = 0.f, s2 = 0.f;
    for (int u = threadIdx.x; u < 2 * HW; u += 256) {
        int b = (u >= HW) ? 1 : 0;
        int p = u - b * HW;
        int y = p >> lg, x = p & (H - 1);
        float fy = (float)y * sc, fx = (float)x * sc;
        int y0 = (int)fy, x0 = (int)fx;
        int y1 = min(y0 + 1, 31), x1 = min(x0 + 1, 31);
        float wy = fy - (float)y0, wx = fx - (float)x0;
        const unsigned short* src = fsm + ((size_t)(lvl * 2 + b) * 256 + c) * 1024;
        float a = bf2f(src[y0 * 32 + x0]), bb = bf2f(src[y1 * 32 + x0]);
        float cc = bf2f(src[y0 * 32 + x1]), d = bf2f(src[y1 * 32 + x1]);
        float c0 = a + (bb - a) * wy;
        float c1 = cc + (d - cc) * wy;
        float v = c0 + (c1 - c0) * wx;
        s += v; s2 += v * v;
    }
#pragma unroll
    for (int off = 32; off; off >>= 1) {
        s  += __shfl_xor(s, off);
        s2 += __shfl_xor(s2, off);
    }
    __shared__ float r1[4], r2[4];
    if ((threadIdx.x & 63) == 0) { r1[threadIdx.x >> 6] = s; r2[threadIdx.x >> 6] = s2; }
    __syncthreads();
    if (threadIdx.x == 0) {
        float cnt = 2.f * (float)HW;
        float mm = (r1[0] + r1[1] + r1[2] + r1[3]) / cnt;
        float qq = (r2[0] + r2[1] + r2[2] + r2[3]) / cnt;
        mu[lvl * 256 + c] = mm; var[lvl * 256 + c] = qq - mm * mm;
    }
}

// ---------------- fold BN into comb weights, all levels ----------------
__global__ __launch_bounds__(256) void prep_comb_all(
    const float* __restrict__ comb_w, const float* __restrict__ comb_b,
    const float* __restrict__ gamma, const float* __restrict__ beta,
    const float* __restrict__ mu, const float* __restrict__ var,
    short* __restrict__ wc, float* __restrict__ bias2)
{
    const int oc = blockIdx.x, lvl = blockIdx.y;
    const int ic = threadIdx.x;
    float a  = gamma[lvl * 256 + ic] * rsqrtf(var[lvl * 256 + ic] + 1e-5f);
    float bb = beta[lvl * 256 + ic] - mu[lvl * 256 + ic] * a;
    float w1 = comb_w[(size_t)oc * 512 + ic];
    float w2 = comb_w[(size_t)oc * 512 + 256 + ic];
    short* wcl = wc + (size_t)lvl * 131072;
    wcl[(size_t)oc * 512 + ic]       = (short)f2bf(w1);
    wcl[(size_t)oc * 512 + 256 + ic] = (short)f2bf(w2 * a);
    float s = w2 * bb;
#pragma unroll
    for (int off = 32; off; off >>= 1) s += __shfl_xor(s, off);
    __shared__ float red[4];
    if ((threadIdx.x & 63) == 0) red[threadIdx.x >> 6] = s;
    __syncthreads();
    if (threadIdx.x == 0)
        bias2[lvl * 256 + oc] = comb_b[oc] + red[0] + red[1] + red[2] + red[3];
}

// ---------------- comb 1x1 conv, all levels, fin upsampled inline from fsm ----------------
// grid (171, 2): x 0-127 -> L0, 128-159 -> L1, 160-167 -> L2, 168-169 -> L3, 170 -> L4
__global__ __launch_bounds__(256, 1) void comb_all(
    const float* f0, const float* f1, const float* f2, const float* f3, const float* f4,
    const unsigned short* __restrict__ fsm,  // [5][2][256][1024] bf16
    const short* __restrict__ wc_all,        // [5][256][512] bf16
    const float* __restrict__ bias2_all,     // [5][256]
    float* __restrict__ out)
{
    __shared__ short s_wc[256 * 40];
    __shared__ short s_xc[128 * 40];
    const int bx = blockIdx.x;
    int lvl, x0;
    if      (bx < 128) { lvl = 0; x0 = bx; }
    else if (bx < 160) { lvl = 1; x0 = bx - 128; }
    else if (bx < 168) { lvl = 2; x0 = bx - 160; }
    else if (bx < 170) { lvl = 3; x0 = bx - 168; }
    else               { lvl = 4; x0 = bx - 170; }
    const int H = 128 >> lvl, HW = H * H;
    const int lg = 7 - lvl, Hm = H - 1;
    const float scl = 31.f / (float)Hm;
    static const size_t CUM[5] = {0, 8388608, 10485760, 11010048, 11141120};
    const float* f = sel5(f0, f1, f2, f3, f4, lvl);
    const short* wc = wc_all + (size_t)lvl * 131072;
    const float* bias2 = bias2_all + lvl * 256;
    float* outl = out + CUM[lvl];

    const int tid = threadIdx.x;
    const int p0 = x0 * 128;
    const int b  = blockIdx.y;
    const int wv = tid >> 6, l31 = tid & 31, lh = (tid >> 5) & 1;
    const int wm = wv >> 1, wn = wv & 1;

    f32x16 acc[4][2];
#pragma unroll
    for (int i = 0; i < 4; ++i)
#pragma unroll
        for (int j = 0; j < 2; ++j)
#pragma unroll
            for (int r = 0; r < 16; ++r) acc[i][j][r] = 0.f;

    for (int k0 = 0; k0 < 512; k0 += 32) {
        __syncthreads();
        for (int u = tid; u < 512; u += 256) {
            int r = u >> 1, h = u & 1;
            *(bf16x8*)&s_wc[r * 40 + h * 16 + 0] = *(const bf16x8*)&wc[(size_t)r * 512 + k0 + h * 16];
            *(bf16x8*)&s_wc[r * 40 + h * 16 + 8] = *(const bf16x8*)&wc[(size_t)r * 512 + k0 + h * 16 + 8];
        }
        for (int u = tid; u < 1024; u += 256) {
            int kr = u >> 5, n4 = (u & 31) * 4;
            int ck = k0 + kr;
            if (ck < 256) {
                const float* bsrc = f + ((size_t)(b * 256 + ck)) * HW;
                int p = p0 + n4;
                float v0, v1, v2, v3;
                if (p + 3 < HW) {
                    float4 v4 = *(const float4*)&bsrc[p];
                    v0 = v4.x; v1 = v4.y; v2 = v4.z; v3 = v4.w;
                } else {
                    v0 = bsrc[min(p,     HW - 1)];
                    v1 = bsrc[min(p + 1, HW - 1)];
                    v2 = bsrc[min(p + 2, HW - 1)];
                    v3 = bsrc[min(p + 3, HW - 1)];
                }
                s_xc[(n4 + 0) * 40 + kr] = (short)f2bf(v0);
                s_xc[(n4 + 1) * 40 + kr] = (short)f2bf(v1);
                s_xc[(n4 + 2) * 40 + kr] = (short)f2bf(v2);
                s_xc[(n4 + 3) * 40 + kr] = (short)f2bf(v3);
            } else {
                int c = ck - 256;
                const unsigned short* src = fsm + ((size_t)(lvl * 2 + b) * 256 + c) * 1024;
#pragma unroll
                for (int j = 0; j < 4; ++j) {
                    int pp = min(p0 + n4 + j, HW - 1);
                    int y = pp >> lg, x = pp & Hm;
                    float fy = (float)y * scl, fx = (float)x * scl;
                    int y0 = (int)fy, x0i = (int)fx;
                    int y1 = min(y0 + 1, 31), x1 = min(x0i + 1, 31);
                    float wy = fy - (float)y0, wx = fx - (float)x0i;
                    float a = bf2f(src[y0 * 32 + x0i]), bb = bf2f(src[y1 * 32 + x0i]);
                    float cc = bf2f(src[y0 * 32 + x1]), d = bf2f(src[y1 * 32 + x1]);
                    float c0 = a + (bb - a) * wy;
                    float c1 = cc + (d - cc) * wy;
                    s_xc[(n4 + j) * 40 + kr] = (short)f2bf(c0 + (c1 - c0) * wx);
                }
            }
        }
        __syncthreads();
#pragma unroll
        for (int ks = 0; ks < 2; ++ks) {
            bf16x8 a[4], bx2[2];
#pragma unroll
            for (int mi = 0; mi < 4; ++mi)
                a[mi] = *(const bf16x8*)&s_wc[(wm * 128 + mi * 32 + l31) * 40 + ks * 16 + lh * 8];
#pragma unroll
            for (int ni = 0; ni < 2; ++ni)
                bx2[ni] = *(const bf16x8*)&s_xc[(wn * 64 + ni * 32 + l31) * 40 + ks * 16 + lh * 8];
#pragma unroll
            for (int mi = 0; mi < 4; ++mi)
#pragma unroll
                for (int ni = 0; ni < 2; ++ni)
                    acc[mi][ni] = __builtin_amdgcn_mfma_f32_32x32x16_bf16(a[mi], bx2[ni], acc[mi][ni], 0, 0, 0);
        }
    }
#pragma unroll
    for (int mi = 0; mi < 4; ++mi) {
#pragma unroll
        for (int ni = 0; ni < 2; ++ni) {
            int p = p0 + wn * 64 + ni * 32 + l31;
            if (p < HW) {
#pragma unroll
                for (int r = 0; r < 16; ++r) {
                    int oc = wm * 128 + mi * 32 + (r & 3) + 8 * (r >> 2) + 4 * lh;
                    outl[((size_t)(b * 256 + oc)) * HW + p] = acc[mi][ni][r] + bias2[oc];
                }
            }
        }
    }
}

// ---------------- host orchestration ----------------
extern "C" void kernel_launch(void* const* d_in, const int* in_sizes, int n_in,
                              void* d_out, int out_size, void* d_ws, size_t ws_size,
                              hipStream_t stream) {
    if (ws_size < WS_BYTES) return;

    const float* feats[5];
    for (int i = 0; i < 5; ++i) feats[i] = (const float*)d_in[i];
    const float* attn     = (const float*)d_in[5];
    const float* key_t_w  = (const float*)d_in[6];
    const float* key_t_b  = (const float*)d_in[7];
    const float* val_t_w  = (const float*)d_in[8];
    const float* val_t_b  = (const float*)d_in[9];
    const float* key_q_w  = (const float*)d_in[10];
    const float* key_q_b  = (const float*)d_in[11];
    const float* val_q_w  = (const float*)d_in[12];
    const float* val_q_b  = (const float*)d_in[13];
    const float* bn_gamma = (const float*)d_in[14];
    const float* bn_beta  = (const float*)d_in[15];
    const float* comb_w   = (const float*)d_in[16];
    const float* comb_b   = (const float*)d_in[17];

    char* ws = (char*)d_ws;
    float* biasc = (float*)(ws + B_BIASC);
    unsigned short* kt_hi = (unsigned short*)(ws + B_KTH);
    unsigned short* kt_lo = (unsigned short*)(ws + B_KTL);
    unsigned short* vt    = (unsigned short*)(ws + B_VT);
    unsigned short* kq_hi = (unsigned short*)(ws + B_KQH);
    unsigned short* kq_lo = (unsigned short*)(ws + B_KQL);
    unsigned short* vq    = (unsigned short*)(ws + B_VQ);
    float* mean_f = (float*)(ws + B_MEAN);
    unsigned short* fsm = (unsigned short*)(ws + B_FSM);
    float* mu     = (float*)(ws + B_MU);
    float* var    = (float*)(ws + B_VAR);
    short* wc_bf  = (short*)(ws + B_WC);
    float* bias2  = (float*)(ws + B_BIAS2);
    unsigned short* X_h = (unsigned short*)(ws + B_UNION + U_XH);
    unsigned short* X_l = (unsigned short*)(ws + B_UNION + U_XL);
    short* wp_hi = (short*)(ws + B_UNION + U_WPH);
    short* wp_lo = (short*)(ws + B_UNION + U_WPL);
    unsigned short* part2 = (unsigned short*)(ws + B_UNION + U_FPART);
    float2* ml_arr = (float2*)(ws + B_ML);

    prep_weights<<<dim3(160, 6), 256, 0, stream>>>(
        key_t_w, key_t_b, val_t_w, val_t_b, key_q_w, key_q_b, val_q_w, val_q_b,
        wp_hi, wp_lo, biasc);

    transpose_split<<<dim3(20, 16, 4), 256, 0, stream>>>(attn, X_h, X_l);

    mean2d_all<<<dim3(512, 5), 256, 0, stream>>>(
        feats[0], feats[1], feats[2], feats[3], feats[4], mean_f);

    resizeT_all<<<dim3(2, 16, 20), 256, 0, stream>>>(
        feats[0], feats[1], feats[2], feats[3], feats[4], mean_f, X_h, X_l);

    conv3x3_all<<<2560, 256, 0, stream>>>(
        X_h, X_l, wp_hi, wp_lo, biasc, kt_hi, kt_lo, vt, kq_hi, kq_lo, vq);

    for (int idx = 0; idx < 5; ++idx) {
        flash5<<<dim3(16, 2, 40), 256, 0, stream>>>(
            kt_hi, kt_lo, vt,
            kq_hi + (size_t)idx * 2 * 32768,
            kq_lo + (size_t)idx * 2 * 32768,
            vq + (size_t)idx * 2 * 131072,
            part2, ml_arr);

        reduce40_merge<<<2048, 256, 0, stream>>>(part2, ml_arr, fsm + (size_t)idx * 524288);
    }

    bnstats2_all<<<dim3(256, 5), 256, 0, stream>>>(fsm, mu, var);

    prep_comb_all<<<dim3(256, 5), 256, 0, stream>>>(
        comb_w, comb_b, bn_gamma, bn_beta, mu, var, wc_bf, bias2);

    comb_all<<<dim3(171, 2), 256, 0, stream>>>(
        feats[0], feats[1], feats[2], feats[3], feats[4],
        fsm, wc_bf, bias2, (float*)d_out);
}